// Round 6
// baseline (676.984 us; speedup 1.0000x reference)
//
#include <hip/hip_runtime.h>
#include <hip/hip_bf16.h>
#include <stdint.h>

// Problem: h_t = Lam @ h_{t-1} + B @ x_t ; BS=16, T=4096, D=256, fp32 in/out.
// Two-level chunked scan: level-1 chunks c=64 (C=64), level-2 superchunks of 8.
// R8 (from R7's 433us):
//  (a) pow_chain: the 9 serial pow_round launches + pack2_init fused into ONE
//      128-block persistent kernel with device barriers (gbar) between rounds.
//      Same per-round parallelism as the launch version (<=128 jobs/round);
//      replaces 9 launch/teardowns with ~1-2us barriers.
//  (b) summary GEMM: split-K reduction fused into the epilogue (last-block
//      pattern) -> reduce_s2 launch eliminated.
// Numerics identical to R7 (absmax 2.0 preserved). 18 launches -> 10.

#define CHUNK  64
#define NPB    128   // pow_chain block count

typedef short v8s __attribute__((ext_vector_type(8)));   // 8 x bf16 (4 VGPRs)
typedef float v4f __attribute__((ext_vector_type(4)));   // MFMA accum

static __device__ __forceinline__ unsigned short f2u(float f) {
  union { float f; unsigned int u; } x; x.f = f;
  unsigned int u = x.u + 0x7FFFu + ((x.u >> 16) & 1u);   // RNE f32->bf16
  return (unsigned short)(u >> 16);
}
static __device__ __forceinline__ float u2f(unsigned short h) {
  union { unsigned int u; float f; } x; x.u = ((unsigned int)h) << 16;
  return x.f;
}
// Workgroup barrier that only drains LDS (lgkmcnt), leaving vmcnt free-running
// so register prefetch loads survive across it.
static __device__ __forceinline__ void lds_barrier() {
  asm volatile("s_waitcnt lgkmcnt(0)\n\ts_barrier" ::: "memory");
}
// Device-scope barrier among the NPB pow_chain blocks. One counter per phase;
// counters zeroed by pack_init each launch/replay (graph-safe).
static __device__ __forceinline__ void gbar(unsigned* c) {
  __threadfence();
  __syncthreads();
  if (threadIdx.x == 0) {
    atomicAdd(c, 1u);
    while (__hip_atomic_load(c, __ATOMIC_RELAXED, __HIP_MEMORY_SCOPE_AGENT) < NPB)
      __builtin_amdgcn_s_sleep(2);
    __threadfence();
  }
  __syncthreads();
}

// ---------------------------------------------------------------------------
// Generic 64x64-tile bf16 MFMA GEMM, depth-1 software-pipelined staging.
// A: f32 or bf16 row-major [M,K] (lda). B: bf16 row-major [K,N] (ldb).
// C: f32 or bf16 [M,N] (ldc). blockIdx = (n_tile, m_tile, k_split).
// ADD_C: C += A*B (f32). Numerics identical to the unpipelined version.
// ---------------------------------------------------------------------------
template<bool A_F32, bool C_BF16, bool ADD_C>
__global__ __launch_bounds__(256) void gemm_tile(
    const void* __restrict__ Ap, const unsigned short* __restrict__ Bp,
    void* __restrict__ Cp, int lda, int ldb, int ldc, int Kper, long csplit)
{
  __shared__ unsigned short As[64][72];   // [m][k], pad to kill bank conflicts
  __shared__ unsigned short Bst[64][72];  // [n][k] (transposed for b128 frag reads)
  const int tid = threadIdx.x;
  const int lane = tid & 63, w = tid >> 6;       // 4 waves
  const int q = lane >> 4, ln = lane & 15;
  const long n0 = (long)blockIdx.x * 64;
  const long m0 = (long)blockIdx.y * 64;
  const int  kz = blockIdx.z;
  const long kbase = (long)kz * Kper;
  const int sm = tid >> 2;          // staging row 0..63
  const int sk = (tid & 3) << 4;    // staging col 0,16,32,48

  v4f acc[4];
#pragma unroll
  for (int i = 0; i < 4; ++i) acc[i] = 0;

  float4 fA[4];
  v8s aR0, aR1, bR0, bR1;

  auto load_tile = [&](long kg) {
    if (A_F32) {
      const float* A = (const float*)Ap + (m0 + sm) * (long)lda + kg + sk;
#pragma unroll
      for (int t = 0; t < 4; ++t) fA[t] = ((const float4*)A)[t];
    } else {
      const unsigned short* A = (const unsigned short*)Ap + (m0 + sm) * (long)lda + kg + sk;
      aR0 = ((const v8s*)A)[0]; aR1 = ((const v8s*)A)[1];
    }
    const unsigned short* Bg = Bp + (kg + sm) * (long)ldb + n0 + sk;
    bR0 = ((const v8s*)Bg)[0]; bR1 = ((const v8s*)Bg)[1];
  };

  load_tile(kbase);

  for (int ks = 0; ks < Kper; ks += 64) {
    __syncthreads();
    if (A_F32) {
      unsigned short* d = &As[sm][sk];
#pragma unroll
      for (int t = 0; t < 4; ++t) {
        d[4*t+0] = f2u(fA[t].x); d[4*t+1] = f2u(fA[t].y);
        d[4*t+2] = f2u(fA[t].z); d[4*t+3] = f2u(fA[t].w);
      }
    } else {
      *(v8s*)&As[sm][sk] = aR0; *(v8s*)&As[sm][sk + 8] = aR1;
    }
#pragma unroll
    for (int r = 0; r < 8; ++r) Bst[sk + r][sm] = (unsigned short)bR0[r];
#pragma unroll
    for (int r = 0; r < 8; ++r) Bst[sk + 8 + r][sm] = (unsigned short)bR1[r];
    __syncthreads();
    if (ks + 64 < Kper) load_tile(kbase + ks + 64);
#pragma unroll
    for (int kb = 0; kb < 64; kb += 32) {
      v8s a = *(const v8s*)&As[w*16 + ln][kb + q*8];
#pragma unroll
      for (int nb = 0; nb < 4; ++nb) {
        v8s b = *(const v8s*)&Bst[nb*16 + ln][kb + q*8];
        acc[nb] = __builtin_amdgcn_mfma_f32_16x16x32_bf16(a, b, acc[nb], 0, 0, 0);
      }
    }
  }
#pragma unroll
  for (int nb = 0; nb < 4; ++nb)
#pragma unroll
    for (int r = 0; r < 4; ++r) {
      const long row = m0 + w*16 + q*4 + r;
      const long col = n0 + nb*16 + ln;
      float v = acc[nb][r];
      if (C_BF16) ((unsigned short*)Cp)[row * (long)ldc + col] = f2u(v);
      else {
        float* Cf = (float*)Cp + (long)kz * csplit;
        if (ADD_C) v += Cf[row * (long)ldc + col];
        Cf[row * (long)ldc + col] = v;
      }
    }
}

// ---------------------------------------------------------------------------
// Chunk-summary GEMM with FUSED split-K reduction (last-block pattern):
// S = Bx_r[1024,16384] @ Ghat[16384,256], split-K=8 partials in Spart;
// the 8th block per tile sums partials and scatters bf16 into Acat S-region:
//   s_{b, i=8m+u}[e] -> Acat[b*8+m][256 + u*256 + e]
// ---------------------------------------------------------------------------
__global__ __launch_bounds__(256) void gemm_sum(
    const unsigned short* __restrict__ Bx, const unsigned short* __restrict__ Ghat,
    float* __restrict__ Spart, unsigned short* __restrict__ Acat,
    unsigned int* __restrict__ tilecnt)
{
  __shared__ unsigned short As[64][72];
  __shared__ unsigned short Bst[64][72];
  __shared__ unsigned int oldsh;
  const int tid = threadIdx.x, lane = tid & 63, w = tid >> 6;
  const int q = lane >> 4, ln = lane & 15;
  const long n0 = (long)blockIdx.x * 64;
  const long m0 = (long)blockIdx.y * 64;
  const int  kz = blockIdx.z;
  const long kbase = (long)kz * 2048;
  const int sm = tid >> 2, sk = (tid & 3) << 4;
  v4f acc[4];
#pragma unroll
  for (int i = 0; i < 4; ++i) acc[i] = 0;

  v8s aR0, aR1, bR0, bR1;
  auto load_tile = [&](long kg) {
    const unsigned short* A = Bx + (m0 + sm) * 16384L + kg + sk;
    aR0 = ((const v8s*)A)[0]; aR1 = ((const v8s*)A)[1];
    const unsigned short* Bg = Ghat + (kg + sm) * 256L + n0 + sk;
    bR0 = ((const v8s*)Bg)[0]; bR1 = ((const v8s*)Bg)[1];
  };

  load_tile(kbase);
  for (int ks = 0; ks < 2048; ks += 64) {
    __syncthreads();
    *(v8s*)&As[sm][sk] = aR0; *(v8s*)&As[sm][sk + 8] = aR1;
#pragma unroll
    for (int r = 0; r < 8; ++r) Bst[sk + r][sm] = (unsigned short)bR0[r];
#pragma unroll
    for (int r = 0; r < 8; ++r) Bst[sk + 8 + r][sm] = (unsigned short)bR1[r];
    __syncthreads();
    if (ks + 64 < 2048) load_tile(kbase + ks + 64);
#pragma unroll
    for (int kb = 0; kb < 64; kb += 32) {
      v8s a = *(const v8s*)&As[w*16 + ln][kb + q*8];
#pragma unroll
      for (int nb = 0; nb < 4; ++nb) {
        v8s b = *(const v8s*)&Bst[nb*16 + ln][kb + q*8];
        acc[nb] = __builtin_amdgcn_mfma_f32_16x16x32_bf16(a, b, acc[nb], 0, 0, 0);
      }
    }
  }
  // write this split's partial
#pragma unroll
  for (int nb = 0; nb < 4; ++nb)
#pragma unroll
    for (int r = 0; r < 4; ++r) {
      const long row = m0 + w*16 + q*4 + r;
      const long col = n0 + nb*16 + ln;
      Spart[(long)kz * 262144 + row * 256 + col] = acc[nb][r];
    }
  // last-block reduction
  __threadfence();
  __syncthreads();
  if (tid == 0)
    oldsh = __hip_atomic_fetch_add(&tilecnt[blockIdx.y * 4 + blockIdx.x], 1u,
                                   __ATOMIC_ACQ_REL, __HIP_MEMORY_SCOPE_AGENT);
  __syncthreads();
  if (oldsh == 7) {
    __threadfence();
#pragma unroll
    for (int nb = 0; nb < 4; ++nb)
#pragma unroll
      for (int r = 0; r < 4; ++r) {
        const long row = m0 + w*16 + q*4 + r;
        const long col = n0 + nb*16 + ln;
        float v = 0;
#pragma unroll
        for (int z = 0; z < 8; ++z) v += Spart[(long)z * 262144 + row * 256 + col];
        const int b = (int)(row >> 6), i = (int)(row & 63);
        const int u = i & 7, m = i >> 3;
        Acat[(size_t)(b*8 + m) * 2304 + 256 + u*256 + (int)col] = f2u(v);
      }
  }
}

// ---------------------------------------------------------------------------
// pack_init: Bt[e][d]=B[d][e], LamT[e][d]=Lam[d][e] (bf16); P_0=I, P_1=Lam hi/lo.
// Also zeroes ALL barrier/tile counters (replay-safe).
// ---------------------------------------------------------------------------
__global__ __launch_bounds__(256) void pack_init(
    const float* __restrict__ Bm, const float* __restrict__ Lam,
    unsigned short* __restrict__ Bt, unsigned short* __restrict__ LamT,
    unsigned short* __restrict__ Phi, unsigned short* __restrict__ Plo,
    unsigned int* __restrict__ cnt)
{
  if (blockIdx.x == 0 && threadIdx.x < 128) cnt[threadIdx.x] = 0;
  const int idx = blockIdx.x * 256 + threadIdx.x;  // 0..65535
  const int e = idx >> 8, d = idx & 255;
  Bt[idx]   = f2u(Bm[d * 256 + e]);
  LamT[idx] = f2u(Lam[d * 256 + e]);
  float v = Lam[idx];                              // idx as (dd,ee) row-major
  unsigned short hi = f2u(v);
  Phi[65536 + idx] = hi;
  Plo[65536 + idx] = f2u(v - u2f(hi));
  const int dd = idx >> 8, ee = idx & 255;
  Phi[idx] = (dd == ee) ? (unsigned short)0x3F80 : (unsigned short)0;
  Plo[idx] = 0;
}

// ---------------------------------------------------------------------------
// Pow-job (device fn): P_{mpow+jj} = P_mpow * P_jj, split-bf16 (hi+lo):
// acc = Ah*Bh + Al*Bh + Ah*Bl (drops lo*lo) -> ~fp32. One 64x64 output tile.
// Depth-1 pipelined over the flattened 12-iteration (seg,ks) loop.
// job -> jj=(job>>4)+1, n0=(job&3)*64, m0=((job>>2)&3)*64.
// ---------------------------------------------------------------------------
static __device__ __forceinline__ void pow_job(
    unsigned short* __restrict__ Phi, unsigned short* __restrict__ Plo,
    int mpow, int job,
    unsigned short (*As)[72], unsigned short (*Bst)[72])
{
  const int tid = threadIdx.x, lane = tid & 63, w = tid >> 6;
  const int q = lane >> 4, ln = lane & 15;
  const int jj = (job >> 4) + 1;
  const int n0 = (job & 3) * 64;
  const int m0 = ((job >> 2) & 3) * 64;
  const unsigned short* Ah = Phi + (size_t)mpow * 65536;
  const unsigned short* Al = Plo + (size_t)mpow * 65536;
  const unsigned short* Bh = Phi + (size_t)jj * 65536;
  const unsigned short* Bl = Plo + (size_t)jj * 65536;
  const int sm = tid >> 2, sk = (tid & 3) << 4;
  v4f acc[4];
#pragma unroll
  for (int i = 0; i < 4; ++i) acc[i] = 0;

  v8s aR0, aR1, bR0, bR1;
  auto load_tile = [&](int it) {
    const int seg = it >> 2, ks = (it & 3) << 6;
    const unsigned short* Asrc = (seg == 1) ? Al : Ah;
    const unsigned short* Bsrc = (seg == 2) ? Bl : Bh;
    const unsigned short* Ag = Asrc + (size_t)(m0 + sm) * 256 + ks + sk;
    aR0 = ((const v8s*)Ag)[0]; aR1 = ((const v8s*)Ag)[1];
    const unsigned short* Bg = Bsrc + (size_t)(ks + sm) * 256 + n0 + sk;
    bR0 = ((const v8s*)Bg)[0]; bR1 = ((const v8s*)Bg)[1];
  };

  load_tile(0);
  for (int it = 0; it < 12; ++it) {
    __syncthreads();
    *(v8s*)&As[sm][sk] = aR0; *(v8s*)&As[sm][sk + 8] = aR1;
#pragma unroll
    for (int r = 0; r < 8; ++r) Bst[sk + r][sm] = (unsigned short)bR0[r];
#pragma unroll
    for (int r = 0; r < 8; ++r) Bst[sk + 8 + r][sm] = (unsigned short)bR1[r];
    __syncthreads();
    if (it + 1 < 12) load_tile(it + 1);
#pragma unroll
    for (int kb = 0; kb < 64; kb += 32) {
      v8s a = *(const v8s*)&As[w*16 + ln][kb + q*8];
#pragma unroll
      for (int nb = 0; nb < 4; ++nb) {
        v8s bb = *(const v8s*)&Bst[nb*16 + ln][kb + q*8];
        acc[nb] = __builtin_amdgcn_mfma_f32_16x16x32_bf16(a, bb, acc[nb], 0, 0, 0);
      }
    }
  }
  const size_t ob = (size_t)(mpow + jj) * 65536;
#pragma unroll
  for (int nb = 0; nb < 4; ++nb)
#pragma unroll
    for (int r = 0; r < 4; ++r) {
      const int row = m0 + w*16 + q*4 + r;
      const int col = n0 + nb*16 + ln;
      float v = acc[nb][r];
      unsigned short hi = f2u(v);
      Phi[ob + (size_t)row*256 + col] = hi;
      Plo[ob + (size_t)row*256 + col] = f2u(v - u2f(hi));
    }
}

// ---------------------------------------------------------------------------
// pow_chain: ALL 9 doubling rounds + pack2_init in one persistent kernel.
// 128 blocks; device barrier (gbar) between rounds. Per-round parallelism is
// identical to the launch version (rounds have <=128 jobs, 1 job/block).
// ---------------------------------------------------------------------------
__global__ __launch_bounds__(256) void pow_chain(
    unsigned short* __restrict__ Phi,  unsigned short* __restrict__ Plo,
    unsigned short* __restrict__ Phi2, unsigned short* __restrict__ Plo2,
    unsigned int* __restrict__ cnt)
{
  __shared__ unsigned short As[64][72];
  __shared__ unsigned short Bst[64][72];
  const int pid = blockIdx.x, tid = threadIdx.x;
  int bar = 0;
  // level-1 powers P_2..P_64 by doubling (6 rounds)
#pragma unroll 1
  for (int mp = 1; mp <= 32; mp <<= 1) {
    for (int job = pid; job < 16 * mp; job += NPB)
      pow_job(Phi, Plo, mp, job, As, Bst);
    gbar(&cnt[bar++]);
  }
  // pack2: P2_0 = I, P2_1 = P_64 (hi/lo)
  for (int idx = pid * 256 + tid; idx < 65536; idx += NPB * 256) {
    const int dd = idx >> 8, ee = idx & 255;
    Phi2[idx] = (dd == ee) ? (unsigned short)0x3F80 : (unsigned short)0;
    Plo2[idx] = 0;
    Phi2[65536 + idx] = Phi[(size_t)64 * 65536 + idx];
    Plo2[65536 + idx] = Plo[(size_t)64 * 65536 + idx];
  }
  gbar(&cnt[bar++]);
  // level-2 powers P2_2..P2_8 (3 rounds)
#pragma unroll 1
  for (int mp = 1; mp <= 4; mp <<= 1) {
    for (int job = pid; job < 16 * mp; job += NPB)
      pow_job(Phi2, Plo2, mp, job, As, Bst);
    gbar(&cnt[bar++]);
  }
}

// ---------------------------------------------------------------------------
// pack_all: fused pack_g (blocks 0..2047) + pack_g2 (blocks 2048..3359).
//  pack_g:  Ghat[(j*256+e)][d] = P_{63-j}[d][e];  Q[e][(j*256+d)] = P_{j+1}[d][e]
//  pack_g2: Qcat[2304][2048], G2[2048][256], LcT2hi/lo[e][d] = P2_8[d][e]
// ---------------------------------------------------------------------------
__global__ __launch_bounds__(256) void pack_all(
    const unsigned short* __restrict__ Phi,
    const unsigned short* __restrict__ Phi2, const unsigned short* __restrict__ Plo2,
    unsigned short* __restrict__ Ghat, unsigned short* __restrict__ Q,
    unsigned short* __restrict__ Qcat, unsigned short* __restrict__ G2,
    unsigned short* __restrict__ LcT2hi, unsigned short* __restrict__ LcT2lo)
{
  __shared__ unsigned short tile[64][65];
  const int tx = threadIdx.x & 63, ty = threadIdx.x >> 6;  // ty 0..3
  const int blk0 = blockIdx.x;
  if (blk0 < 2048) {
    const int blk = blk0;
    int t16, jpar;
    const unsigned short* src;
    if (blk < 1024) { jpar = blk >> 4;            t16 = blk & 15;  src = Phi + (size_t)(63 - jpar) * 65536; }
    else            { int v = blk - 1024; jpar = v >> 4; t16 = v & 15; src = Phi + (size_t)(jpar + 1) * 65536; }
    const int d0 = (t16 & 3) * 64, e0 = (t16 >> 2) * 64;
#pragma unroll
    for (int s = 0; s < 16; ++s)
      tile[ty*16 + s][tx] = src[(size_t)(d0 + ty*16 + s) * 256 + e0 + tx];
    __syncthreads();
    if (blk < 1024) {
#pragma unroll
      for (int s = 0; s < 16; ++s) {
        const int e = e0 + ty*16 + s, d = d0 + tx;
        Ghat[((size_t)(jpar*256 + e)) * 256 + d] = tile[tx][ty*16 + s];
      }
    } else {
#pragma unroll
      for (int s = 0; s < 16; ++s) {
        const int e = e0 + ty*16 + s, d = d0 + tx;
        Q[(size_t)e * 16384 + jpar*256 + d] = tile[tx][ty*16 + s];
      }
    }
    return;
  }
  const int blk = blk0 - 2048;
  if (blk < 1152) {                                  // Qcat: 36x32 tiles of 64x64
    const int rt = blk >> 5, ct = blk & 31;
    const int k0 = rt * 64, c0 = ct * 64;
    const int r = c0 >> 8, d0 = c0 & 255;
    int p = 0, e0 = 0;
    bool zero = false;
    if (k0 < 256) { p = r; e0 = k0; }
    else {
      const int u = (k0 - 256) >> 8; e0 = (k0 - 256) & 255;
      if (u >= r) zero = true; else p = r - 1 - u;
    }
    if (zero) {
#pragma unroll
      for (int s = 0; s < 16; ++s)
        Qcat[(size_t)(k0 + ty*16 + s) * 2048 + c0 + tx] = 0;
      return;
    }
    const unsigned short* src = Phi2 + (size_t)p * 65536;
#pragma unroll
    for (int s = 0; s < 16; ++s)
      tile[ty*16 + s][tx] = src[(size_t)(d0 + ty*16 + s) * 256 + e0 + tx];
    __syncthreads();
#pragma unroll
    for (int s = 0; s < 16; ++s)
      Qcat[(size_t)(k0 + ty*16 + s) * 2048 + c0 + tx] = tile[tx][ty*16 + s];
  } else if (blk < 1280) {                           // G2: 32x4 tiles
    const int t = blk - 1152;
    const int rt = t >> 2, ct = t & 3;
    const int k0 = rt * 64, d0 = ct * 64;
    const int r = k0 >> 8, e0 = k0 & 255;
    const unsigned short* src = Phi2 + (size_t)(7 - r) * 65536;
#pragma unroll
    for (int s = 0; s < 16; ++s)
      tile[ty*16 + s][tx] = src[(size_t)(d0 + ty*16 + s) * 256 + e0 + tx];
    __syncthreads();
#pragma unroll
    for (int s = 0; s < 16; ++s)
      G2[(size_t)(k0 + ty*16 + s) * 256 + d0 + tx] = tile[tx][ty*16 + s];
  } else {                                           // LcT2 hi (16) + lo (16)
    const int t = blk - 1280;
    const int half = t >> 4, t16 = t & 15;
    const int d0 = (t16 & 3) * 64, e0 = (t16 >> 2) * 64;
    const unsigned short* src = (half ? Plo2 : Phi2) + (size_t)8 * 65536;
    unsigned short* dst = half ? LcT2lo : LcT2hi;
#pragma unroll
    for (int s = 0; s < 16; ++s)
      tile[ty*16 + s][tx] = src[(size_t)(d0 + ty*16 + s) * 256 + e0 + tx];
    __syncthreads();
#pragma unroll
    for (int s = 0; s < 16; ++s)
      dst[(size_t)(e0 + ty*16 + s) * 256 + d0 + tx] = tile[tx][ty*16 + s];
  }
}

// ---------------------------------------------------------------------------
// Level-2 sequential combine: 8 steps, ONE workgroup, split-bf16 MFMA.
// A2_{b,m} (state entering superchunk m) written bf16 into Acat cols 0..255.
// ---------------------------------------------------------------------------
__global__ __launch_bounds__(512, 2) void k4b_combine(
    const unsigned short* __restrict__ LcT2hi, const unsigned short* __restrict__ LcT2lo,
    const float* __restrict__ S2, unsigned short* __restrict__ Acat)
{
  __shared__ unsigned short Hhi[16][264];
  __shared__ unsigned short Hlo[16][264];
  const int tid = threadIdx.x, lane = tid & 63, w = tid >> 6;  // 8 waves
  const int q = lane >> 4, ln = lane & 15;

  v8s bhi[8][2], blo[8][2];                       // (Lam^512)^T frags, cols [32w,32w+32)
#pragma unroll
  for (int kk = 0; kk < 8; ++kk)
#pragma unroll
    for (int nb = 0; nb < 2; ++nb) {
      const int n = 32*w + nb*16 + ln;
#pragma unroll
      for (int r = 0; r < 8; ++r) {
        const int k = kk*32 + q*8 + r;
        bhi[kk][nb][r] = (short)LcT2hi[k*256 + n];
        blo[kk][nb][r] = (short)LcT2lo[k*256 + n];
      }
    }
  for (int e = tid; e < 16*264; e += 512) { (&Hhi[0][0])[e] = 0; (&Hlo[0][0])[e] = 0; }
  lds_barrier();

  for (int m = 0; m < 8; ++m) {
    for (int e = tid; e < 4096; e += 512) {
      const int b = e >> 8, d = e & 255;
      Acat[(size_t)(b*8 + m) * 2304 + d] = Hhi[b][d];
    }
    v8s ahi[8], alo[8];
#pragma unroll
    for (int kk = 0; kk < 8; ++kk) {
      ahi[kk] = *(const v8s*)&Hhi[ln][kk*32 + q*8];
      alo[kk] = *(const v8s*)&Hlo[ln][kk*32 + q*8];
    }
    lds_barrier();
    v4f acc[2];
#pragma unroll
    for (int nb = 0; nb < 2; ++nb)
#pragma unroll
      for (int r = 0; r < 4; ++r) {
        const int bb = 4*q + r, col = 32*w + nb*16 + ln;
        acc[nb][r] = S2[(size_t)(bb*8 + m) * 256 + col];
      }
#pragma unroll
    for (int kk = 0; kk < 8; ++kk)
#pragma unroll
      for (int nb = 0; nb < 2; ++nb) {
        acc[nb] = __builtin_amdgcn_mfma_f32_16x16x32_bf16(ahi[kk], bhi[kk][nb], acc[nb], 0, 0, 0);
        acc[nb] = __builtin_amdgcn_mfma_f32_16x16x32_bf16(alo[kk], bhi[kk][nb], acc[nb], 0, 0, 0);
        acc[nb] = __builtin_amdgcn_mfma_f32_16x16x32_bf16(ahi[kk], blo[kk][nb], acc[nb], 0, 0, 0);
      }
#pragma unroll
    for (int nb = 0; nb < 2; ++nb)
#pragma unroll
      for (int r = 0; r < 4; ++r) {
        const int bb = 4*q + r, col = 32*w + nb*16 + ln;
        float v = acc[nb][r];
        unsigned short hi = f2u(v);
        Hhi[bb][col] = hi;
        Hlo[bb][col] = f2u(v - u2f(hi));
      }
    lds_barrier();
  }
}

// ---------------------------------------------------------------------------
// Phase 3: local scan (init 0), writes g_local (fp32) to Out. Carry added
// later by the carry GEMM's += epilogue. Double-buffered state LDS -> ONE
// lds_barrier per step; Bx depth-2 register prefetch. Bit-identical math.
// ---------------------------------------------------------------------------
__global__ __launch_bounds__(256, 1) void k5_scan(
    const unsigned short* __restrict__ LamT,
    const unsigned short* __restrict__ Bx, float* __restrict__ Out)
{
  __shared__ unsigned short gs[2][16][264];
  const int tid = threadIdx.x, lane = tid & 63, w = tid >> 6;  // 4 waves
  const int q = lane >> 4, ln = lane & 15;
  const int blk = blockIdx.x;
  const int b  = blk >> 4;            // batch
  const int i0 = (blk * 4) & 63;      // first chunk index of this block

  v8s bf[8][4];                        // Lam^T frags, cols [64w,64w+64)
#pragma unroll
  for (int kk = 0; kk < 8; ++kk)
#pragma unroll
    for (int nb = 0; nb < 4; ++nb) {
      const int n = 64*w + nb*16 + ln;
#pragma unroll
      for (int r = 0; r < 8; ++r)
        bf[kk][nb][r] = (short)LamT[(kk*32 + q*8 + r) * 256 + n];
    }
  for (int e = tid; e < 16*264; e += 256) (&gs[0][0][0])[e] = 0;  // zero buf 0

  size_t base[4];
#pragma unroll
  for (int r = 0; r < 4; ++r)
    base[r] = ((size_t)b*4096 + (size_t)(i0 + r)*64) * 256;   // row of step j=0
  const int colw = 64*w;

  unsigned short bxr[2][4][4];         // depth-2 Bx prefetch ring (q==0 lanes)
  if (q == 0) {
#pragma unroll
    for (int s = 0; s < 2; ++s)
#pragma unroll
      for (int r = 0; r < 4; ++r)
#pragma unroll
        for (int nb = 0; nb < 4; ++nb)
          bxr[s][r][nb] = Bx[base[r] + (size_t)s*256 + colw + nb*16 + ln];
  }
  lds_barrier();

#pragma unroll 2
  for (int j = 0; j < CHUNK; ++j) {
    v8s a[8];
#pragma unroll
    for (int kk = 0; kk < 8; ++kk) a[kk] = *(const v8s*)&gs[j & 1][ln][kk*32 + q*8];
    v4f acc[4];
#pragma unroll
    for (int nb = 0; nb < 4; ++nb) acc[nb] = 0;
#pragma unroll
    for (int kk = 0; kk < 8; ++kk)
#pragma unroll
      for (int nb = 0; nb < 4; ++nb)
        acc[nb] = __builtin_amdgcn_mfma_f32_16x16x32_bf16(a[kk], bf[kk][nb], acc[nb], 0, 0, 0);
    if (q == 0) {
#pragma unroll
      for (int r = 0; r < 4; ++r) {
        const size_t rb = base[r] + (size_t)j*256 + colw;
#pragma unroll
        for (int nb = 0; nb < 4; ++nb) {
          const float g = acc[nb][r] + u2f(bxr[j & 1][r][nb]);
          Out[rb + nb*16 + ln] = g;
          gs[(j + 1) & 1][r][colw + nb*16 + ln] = f2u(g);   // write OTHER buffer
        }
      }
      if (j < CHUNK - 2) {
#pragma unroll
        for (int r = 0; r < 4; ++r) {
          const size_t rb = base[r] + (size_t)(j + 2)*256 + colw;
#pragma unroll
          for (int nb = 0; nb < 4; ++nb)
            bxr[j & 1][r][nb] = Bx[rb + nb*16 + ln];
        }
      }
    }
    lds_barrier();   // single barrier: new state visible to all waves
  }
}

// ---------------------------------------------------------------------------
extern "C" void kernel_launch(void* const* d_in, const int* in_sizes, int n_in,
                              void* d_out, int out_size, void* d_ws, size_t ws_size,
                              hipStream_t stream)
{
  const float* x   = (const float*)d_in[0];
  const float* Bm  = (const float*)d_in[1];
  const float* Lam = (const float*)d_in[2];
  float* Out = (float*)d_out;
  (void)in_sizes; (void)n_in; (void)out_size; (void)ws_size;

  char* ws = (char*)d_ws;
  size_t off = 0;
  auto alloc = [&](size_t bytes) { void* p = ws + off; off += (bytes + 255) & ~(size_t)255; return p; };
  unsigned short* Bx    = (unsigned short*)alloc((size_t)16777216 * 2);      // 32 MB
  unsigned short* Phi   = (unsigned short*)alloc((size_t)65 * 65536 * 2);    // 8.3 MB
  unsigned short* Plo   = (unsigned short*)alloc((size_t)65 * 65536 * 2);    // 8.3 MB
  unsigned short* Ghat  = (unsigned short*)alloc((size_t)16384 * 256 * 2);   // 8 MB
  unsigned short* Q     = (unsigned short*)alloc((size_t)256 * 16384 * 2);   // 8 MB
  unsigned short* Qcat  = (unsigned short*)alloc((size_t)2304 * 2048 * 2);   // 9.4 MB
  unsigned short* G2    = (unsigned short*)alloc((size_t)2048 * 256 * 2);    // 1 MB
  unsigned short* Phi2  = (unsigned short*)alloc((size_t)9 * 65536 * 2);
  unsigned short* Plo2  = (unsigned short*)alloc((size_t)9 * 65536 * 2);
  unsigned short* Bt    = (unsigned short*)alloc(131072);
  unsigned short* LamT  = (unsigned short*)alloc(131072);
  unsigned short* LcT2hi= (unsigned short*)alloc(131072);
  unsigned short* LcT2lo= (unsigned short*)alloc(131072);
  unsigned short* Acat  = (unsigned short*)alloc((size_t)128 * 2304 * 2);    // 0.6 MB
  float*          S2    = (float*)alloc(131072);
  unsigned short* Abf   = (unsigned short*)alloc(524288);
  unsigned int*   cnt   = (unsigned int*)alloc(512);   // [0..15] pow barriers, [32..95] tiles
  float*          Spart = (float*)Plo;  // alias: Plo dead before summary GEMM writes Spart

  // 1) packs + P0/P1 (+ zero all counters — replay-safe)
  pack_init<<<dim3(256), dim3(256), 0, stream>>>(Bm, Lam, Bt, LamT, Phi, Plo, cnt);
  // 2) Bx = x @ B^T  (bf16 out)
  gemm_tile<true, true, false><<<dim3(4, 1024, 1), dim3(256), 0, stream>>>(
      (const void*)x, Bt, (void*)Bx, 256, 256, 256, 256, 0);
  // 3) local scans: Out = g_local (fp32). Carry added later by GEMM epilogue.
  k5_scan<<<dim3(256), dim3(256), 0, stream>>>(LamT, Bx, Out);
  // 4) ALL powers (level-1 + pack2 + level-2) in one persistent kernel
  pow_chain<<<dim3(NPB), dim3(256), 0, stream>>>(Phi, Plo, Phi2, Plo2, cnt);
  // 5) pack all GEMM operands (fused)
  pack_all<<<dim3(3360), dim3(256), 0, stream>>>(Phi, Phi2, Plo2,
      Ghat, Q, Qcat, G2, LcT2hi, LcT2lo);
  // 6) chunk summaries with fused split-K reduction -> Acat S-region
  gemm_sum<<<dim3(4, 16, 8), dim3(256), 0, stream>>>(Bx, Ghat, Spart, Acat, cnt + 32);
  // 7) level-2 summaries: S2[128,256] = Acat_S[128,2048] @ G2
  gemm_tile<false, false, false><<<dim3(4, 2, 1), dim3(256), 0, stream>>>(
      (const void*)(Acat + 256), G2, (void*)S2, 2304, 256, 256, 2048, 0);
  // 8) sequential combine over 8 superchunks -> A2 into Acat cols 0..255
  k4b_combine<<<dim3(1), dim3(512), 0, stream>>>(LcT2hi, LcT2lo, S2, Acat);
  // 9) all chunk-entry states in one GEMM: Abf[128,2048] = Acat[128,2304] @ Qcat
  gemm_tile<false, true, false><<<dim3(32, 2, 1), dim3(256), 0, stream>>>(
      (const void*)Acat, Qcat, (void*)Abf, 2304, 2048, 2048, 2304, 0);
  // 10) carry GEMM with += epilogue: Out = Abf @ Q + Out(g_local)
  gemm_tile<false, false, true><<<dim3(256, 16, 1), dim3(256), 0, stream>>>(
      (const void*)Abf, Q, (void*)Out, 256, 16384, 16384, 256, 0);
}

// Round 7
// 461.770 us; speedup vs baseline: 1.4661x; 1.4661x over previous
//
#include <hip/hip_runtime.h>
#include <hip/hip_bf16.h>
#include <stdint.h>

// Problem: h_t = Lam @ h_{t-1} + B @ x_t ; BS=16, T=4096, D=256, fp32 in/out.
// Two-level chunked scan: level-1 chunks c=64 (C=64), level-2 superchunks of 8.
// R9: revert R8's two regressions (gbar device barriers cost ~20us each via
// XCD L2 writeback fences -> pow_chain 268us vs ~90us as launches; gemm_sum's
// per-block threadfence same poison). Structure = R7 (433us verified) plus:
//  (a) k5_scan: 512 blocks x 2 chunks (was 256 x 4). Identical per-chunk op
//      order (bit-exact); 2 blocks/CU co-resident so the two blocks' barrier
//      and LDS/MFMA latency phases interleave on the same SIMDs.
//  (b) pack2_init folded into the mp=32 pow_round epilogue (1 launch saved).

#define CHUNK  64

typedef short v8s __attribute__((ext_vector_type(8)));   // 8 x bf16 (4 VGPRs)
typedef float v4f __attribute__((ext_vector_type(4)));   // MFMA accum

static __device__ __forceinline__ unsigned short f2u(float f) {
  union { float f; unsigned int u; } x; x.f = f;
  unsigned int u = x.u + 0x7FFFu + ((x.u >> 16) & 1u);   // RNE f32->bf16
  return (unsigned short)(u >> 16);
}
static __device__ __forceinline__ float u2f(unsigned short h) {
  union { unsigned int u; float f; } x; x.u = ((unsigned int)h) << 16;
  return x.f;
}
// Workgroup barrier that only drains LDS (lgkmcnt), leaving vmcnt free-running
// so register prefetch loads survive across it. Safe when the only cross-wave
// dependency through the barrier is LDS data.
static __device__ __forceinline__ void lds_barrier() {
  asm volatile("s_waitcnt lgkmcnt(0)\n\ts_barrier" ::: "memory");
}

// ---------------------------------------------------------------------------
// Generic 64x64-tile bf16 MFMA GEMM, depth-1 software-pipelined staging.
// A: f32 or bf16 row-major [M,K] (lda). B: bf16 row-major [K,N] (ldb).
// C: f32 or bf16 [M,N] (ldc). blockIdx = (n_tile, m_tile, k_split).
// Per-split K length = Kper. Split partials go to C + z*csplit (f32 path).
// ADD_C: C += A*B (f32). Numerics identical to the unpipelined version.
// ---------------------------------------------------------------------------
template<bool A_F32, bool C_BF16, bool ADD_C>
__global__ __launch_bounds__(256) void gemm_tile(
    const void* __restrict__ Ap, const unsigned short* __restrict__ Bp,
    void* __restrict__ Cp, int lda, int ldb, int ldc, int Kper, long csplit)
{
  __shared__ unsigned short As[64][72];   // [m][k], pad to kill bank conflicts
  __shared__ unsigned short Bst[64][72];  // [n][k] (transposed for b128 frag reads)
  const int tid = threadIdx.x;
  const int lane = tid & 63, w = tid >> 6;       // 4 waves
  const int q = lane >> 4, ln = lane & 15;
  const long n0 = (long)blockIdx.x * 64;
  const long m0 = (long)blockIdx.y * 64;
  const int  kz = blockIdx.z;
  const long kbase = (long)kz * Kper;
  const int sm = tid >> 2;          // staging row 0..63
  const int sk = (tid & 3) << 4;    // staging col 0,16,32,48

  v4f acc[4];
#pragma unroll
  for (int i = 0; i < 4; ++i) acc[i] = 0;

  // staging registers (next K-tile in flight)
  float4 fA[4];
  v8s aR0, aR1, bR0, bR1;

  auto load_tile = [&](long kg) {
    if (A_F32) {
      const float* A = (const float*)Ap + (m0 + sm) * (long)lda + kg + sk;
#pragma unroll
      for (int t = 0; t < 4; ++t) fA[t] = ((const float4*)A)[t];
    } else {
      const unsigned short* A = (const unsigned short*)Ap + (m0 + sm) * (long)lda + kg + sk;
      aR0 = ((const v8s*)A)[0]; aR1 = ((const v8s*)A)[1];
    }
    const unsigned short* Bg = Bp + (kg + sm) * (long)ldb + n0 + sk;
    bR0 = ((const v8s*)Bg)[0]; bR1 = ((const v8s*)Bg)[1];
  };

  load_tile(kbase);                       // prologue: tile ks=0 in regs

  for (int ks = 0; ks < Kper; ks += 64) {
    __syncthreads();                      // prior MFMA phase done with LDS
    // write staged regs -> LDS
    if (A_F32) {
      unsigned short* d = &As[sm][sk];
#pragma unroll
      for (int t = 0; t < 4; ++t) {
        d[4*t+0] = f2u(fA[t].x); d[4*t+1] = f2u(fA[t].y);
        d[4*t+2] = f2u(fA[t].z); d[4*t+3] = f2u(fA[t].w);
      }
    } else {
      *(v8s*)&As[sm][sk] = aR0; *(v8s*)&As[sm][sk + 8] = aR1;
    }
#pragma unroll
    for (int r = 0; r < 8; ++r) Bst[sk + r][sm] = (unsigned short)bR0[r];
#pragma unroll
    for (int r = 0; r < 8; ++r) Bst[sk + 8 + r][sm] = (unsigned short)bR1[r];
    __syncthreads();
    // prefetch next tile into regs — overlaps with the MFMA phase below
    if (ks + 64 < Kper) load_tile(kbase + ks + 64);
#pragma unroll
    for (int kb = 0; kb < 64; kb += 32) {
      v8s a = *(const v8s*)&As[w*16 + ln][kb + q*8];
#pragma unroll
      for (int nb = 0; nb < 4; ++nb) {
        v8s b = *(const v8s*)&Bst[nb*16 + ln][kb + q*8];
        acc[nb] = __builtin_amdgcn_mfma_f32_16x16x32_bf16(a, b, acc[nb], 0, 0, 0);
      }
    }
  }
#pragma unroll
  for (int nb = 0; nb < 4; ++nb)
#pragma unroll
    for (int r = 0; r < 4; ++r) {
      const long row = m0 + w*16 + q*4 + r;        // D row = 4q+r within wave's 16
      const long col = n0 + nb*16 + ln;
      float v = acc[nb][r];
      if (C_BF16) ((unsigned short*)Cp)[row * (long)ldc + col] = f2u(v);
      else {
        float* Cf = (float*)Cp + (long)kz * csplit;
        if (ADD_C) v += Cf[row * (long)ldc + col];
        Cf[row * (long)ldc + col] = v;
      }
    }
}

// ---------------------------------------------------------------------------
// Powers by doubling, split-bf16 (hi+lo): P_{mpow+jj} = P_mpow * P_jj,
// jj=1..mpow.  acc = Ah*Bh + Al*Bh + Ah*Bl (drops lo*lo) -> ~fp32.
// Depth-1 pipelined over the flattened 12-iteration (seg,ks) loop.
// Fused pack2 init: at mpow==32, jj==32 blocks also write P2_1 = P_64 (hi/lo)
// and jj==1 blocks write P2_0 = I. (Phi2/Plo2 unused for other rounds.)
// ---------------------------------------------------------------------------
__global__ __launch_bounds__(256) void pow_round(
    unsigned short* __restrict__ Phi, unsigned short* __restrict__ Plo, int mpow,
    unsigned short* __restrict__ Phi2, unsigned short* __restrict__ Plo2)
{
  __shared__ unsigned short As[64][72];
  __shared__ unsigned short Bst[64][72];
  const int tid = threadIdx.x, lane = tid & 63, w = tid >> 6;
  const int q = lane >> 4, ln = lane & 15;
  const int jj = (blockIdx.x >> 2) + 1;
  const int n0 = (blockIdx.x & 3) * 64;
  const int m0 = blockIdx.y * 64;
  const unsigned short* Ah = Phi + (size_t)mpow * 65536;
  const unsigned short* Al = Plo + (size_t)mpow * 65536;
  const unsigned short* Bh = Phi + (size_t)jj * 65536;
  const unsigned short* Bl = Plo + (size_t)jj * 65536;
  const int sm = tid >> 2, sk = (tid & 3) << 4;
  v4f acc[4];
#pragma unroll
  for (int i = 0; i < 4; ++i) acc[i] = 0;

  v8s aR0, aR1, bR0, bR1;
  auto load_tile = [&](int it) {
    const int seg = it >> 2, ks = (it & 3) << 6;
    const unsigned short* Asrc = (seg == 1) ? Al : Ah;
    const unsigned short* Bsrc = (seg == 2) ? Bl : Bh;
    const unsigned short* Ag = Asrc + (size_t)(m0 + sm) * 256 + ks + sk;
    aR0 = ((const v8s*)Ag)[0]; aR1 = ((const v8s*)Ag)[1];
    const unsigned short* Bg = Bsrc + (size_t)(ks + sm) * 256 + n0 + sk;
    bR0 = ((const v8s*)Bg)[0]; bR1 = ((const v8s*)Bg)[1];
  };

  load_tile(0);
  for (int it = 0; it < 12; ++it) {
    __syncthreads();
    *(v8s*)&As[sm][sk] = aR0; *(v8s*)&As[sm][sk + 8] = aR1;
#pragma unroll
    for (int r = 0; r < 8; ++r) Bst[sk + r][sm] = (unsigned short)bR0[r];
#pragma unroll
    for (int r = 0; r < 8; ++r) Bst[sk + 8 + r][sm] = (unsigned short)bR1[r];
    __syncthreads();
    if (it + 1 < 12) load_tile(it + 1);   // overlaps with MFMA below
#pragma unroll
    for (int kb = 0; kb < 64; kb += 32) {
      v8s a = *(const v8s*)&As[w*16 + ln][kb + q*8];
#pragma unroll
      for (int nb = 0; nb < 4; ++nb) {
        v8s bb = *(const v8s*)&Bst[nb*16 + ln][kb + q*8];
        acc[nb] = __builtin_amdgcn_mfma_f32_16x16x32_bf16(a, bb, acc[nb], 0, 0, 0);
      }
    }
  }
  const size_t ob = (size_t)(mpow + jj) * 65536;
#pragma unroll
  for (int nb = 0; nb < 4; ++nb)
#pragma unroll
    for (int r = 0; r < 4; ++r) {
      const int row = m0 + w*16 + q*4 + r;
      const int col = n0 + nb*16 + ln;
      float v = acc[nb][r];
      unsigned short hi = f2u(v);
      Phi[ob + (size_t)row*256 + col] = hi;
      Plo[ob + (size_t)row*256 + col] = f2u(v - u2f(hi));
      if (mpow == 32) {                       // fused pack2 init
        if (jj == 32) {                       // P2_1 = P_64 (this result)
          Phi2[65536 + (size_t)row*256 + col] = hi;
          Plo2[65536 + (size_t)row*256 + col] = f2u(v - u2f(hi));
        } else if (jj == 1) {                 // P2_0 = I (tile m0,n0)
          Phi2[(size_t)row*256 + col] = (row == col) ? (unsigned short)0x3F80 : (unsigned short)0;
          Plo2[(size_t)row*256 + col] = 0;
        }
      }
    }
}

// ---------------------------------------------------------------------------
// pack_init: Bt[e][d]=B[d][e], LamT[e][d]=Lam[d][e] (bf16); P_0=I, P_1=Lam hi/lo.
// ---------------------------------------------------------------------------
__global__ __launch_bounds__(256) void pack_init(
    const float* __restrict__ Bm, const float* __restrict__ Lam,
    unsigned short* __restrict__ Bt, unsigned short* __restrict__ LamT,
    unsigned short* __restrict__ Phi, unsigned short* __restrict__ Plo)
{
  const int idx = blockIdx.x * 256 + threadIdx.x;  // 0..65535
  const int e = idx >> 8, d = idx & 255;
  Bt[idx]   = f2u(Bm[d * 256 + e]);
  LamT[idx] = f2u(Lam[d * 256 + e]);
  float v = Lam[idx];                              // idx as (dd,ee) row-major
  unsigned short hi = f2u(v);
  Phi[65536 + idx] = hi;
  Plo[65536 + idx] = f2u(v - u2f(hi));
  const int dd = idx >> 8, ee = idx & 255;
  Phi[idx] = (dd == ee) ? (unsigned short)0x3F80 : (unsigned short)0;
  Plo[idx] = 0;
}

// ---------------------------------------------------------------------------
// pack_all: fused pack_g (blocks 0..2047) + pack_g2 (blocks 2048..3359).
//  pack_g:  Ghat[(j*256+e)][d] = P_{63-j}[d][e];  Q[e][(j*256+d)] = P_{j+1}[d][e]
//  pack_g2: Qcat[2304][2048], G2[2048][256], LcT2hi/lo[e][d] = P2_8[d][e]
// ---------------------------------------------------------------------------
__global__ __launch_bounds__(256) void pack_all(
    const unsigned short* __restrict__ Phi,
    const unsigned short* __restrict__ Phi2, const unsigned short* __restrict__ Plo2,
    unsigned short* __restrict__ Ghat, unsigned short* __restrict__ Q,
    unsigned short* __restrict__ Qcat, unsigned short* __restrict__ G2,
    unsigned short* __restrict__ LcT2hi, unsigned short* __restrict__ LcT2lo)
{
  __shared__ unsigned short tile[64][65];
  const int tx = threadIdx.x & 63, ty = threadIdx.x >> 6;  // ty 0..3
  const int blk0 = blockIdx.x;
  if (blk0 < 2048) {
    const int blk = blk0;
    int t16, jpar;
    const unsigned short* src;
    if (blk < 1024) { jpar = blk >> 4;            t16 = blk & 15;  src = Phi + (size_t)(63 - jpar) * 65536; }
    else            { int v = blk - 1024; jpar = v >> 4; t16 = v & 15; src = Phi + (size_t)(jpar + 1) * 65536; }
    const int d0 = (t16 & 3) * 64, e0 = (t16 >> 2) * 64;
#pragma unroll
    for (int s = 0; s < 16; ++s)
      tile[ty*16 + s][tx] = src[(size_t)(d0 + ty*16 + s) * 256 + e0 + tx];
    __syncthreads();
    if (blk < 1024) {
#pragma unroll
      for (int s = 0; s < 16; ++s) {
        const int e = e0 + ty*16 + s, d = d0 + tx;
        Ghat[((size_t)(jpar*256 + e)) * 256 + d] = tile[tx][ty*16 + s];
      }
    } else {
#pragma unroll
      for (int s = 0; s < 16; ++s) {
        const int e = e0 + ty*16 + s, d = d0 + tx;
        Q[(size_t)e * 16384 + jpar*256 + d] = tile[tx][ty*16 + s];
      }
    }
    return;
  }
  const int blk = blk0 - 2048;
  if (blk < 1152) {                                  // Qcat: 36x32 tiles of 64x64
    const int rt = blk >> 5, ct = blk & 31;
    const int k0 = rt * 64, c0 = ct * 64;
    const int r = c0 >> 8, d0 = c0 & 255;
    int p = 0, e0 = 0;
    bool zero = false;
    if (k0 < 256) { p = r; e0 = k0; }
    else {
      const int u = (k0 - 256) >> 8; e0 = (k0 - 256) & 255;
      if (u >= r) zero = true; else p = r - 1 - u;
    }
    if (zero) {
#pragma unroll
      for (int s = 0; s < 16; ++s)
        Qcat[(size_t)(k0 + ty*16 + s) * 2048 + c0 + tx] = 0;
      return;
    }
    const unsigned short* src = Phi2 + (size_t)p * 65536;
#pragma unroll
    for (int s = 0; s < 16; ++s)
      tile[ty*16 + s][tx] = src[(size_t)(d0 + ty*16 + s) * 256 + e0 + tx];
    __syncthreads();
#pragma unroll
    for (int s = 0; s < 16; ++s)
      Qcat[(size_t)(k0 + ty*16 + s) * 2048 + c0 + tx] = tile[tx][ty*16 + s];
  } else if (blk < 1280) {                           // G2: 32x4 tiles
    const int t = blk - 1152;
    const int rt = t >> 2, ct = t & 3;
    const int k0 = rt * 64, d0 = ct * 64;
    const int r = k0 >> 8, e0 = k0 & 255;
    const unsigned short* src = Phi2 + (size_t)(7 - r) * 65536;
#pragma unroll
    for (int s = 0; s < 16; ++s)
      tile[ty*16 + s][tx] = src[(size_t)(d0 + ty*16 + s) * 256 + e0 + tx];
    __syncthreads();
#pragma unroll
    for (int s = 0; s < 16; ++s)
      G2[(size_t)(k0 + ty*16 + s) * 256 + d0 + tx] = tile[tx][ty*16 + s];
  } else {                                           // LcT2 hi (16) + lo (16)
    const int t = blk - 1280;
    const int half = t >> 4, t16 = t & 15;
    const int d0 = (t16 & 3) * 64, e0 = (t16 >> 2) * 64;
    const unsigned short* src = (half ? Plo2 : Phi2) + (size_t)8 * 65536;
    unsigned short* dst = half ? LcT2lo : LcT2hi;
#pragma unroll
    for (int s = 0; s < 16; ++s)
      tile[ty*16 + s][tx] = src[(size_t)(d0 + ty*16 + s) * 256 + e0 + tx];
    __syncthreads();
#pragma unroll
    for (int s = 0; s < 16; ++s)
      dst[(size_t)(e0 + ty*16 + s) * 256 + d0 + tx] = tile[tx][ty*16 + s];
  }
}

// ---------------------------------------------------------------------------
// reduce split-K partials and scatter into Acat (bf16) S-region:
// s_{b, i=8m+u}[e] -> Acat[b*8+m][256 + u*256 + e]
// ---------------------------------------------------------------------------
__global__ __launch_bounds__(256) void reduce_s2(
    const float* __restrict__ Sp, unsigned short* __restrict__ Acat)
{
  const int f = blockIdx.x * 256 + threadIdx.x;   // 262144 total
  float v = 0;
#pragma unroll
  for (int z = 0; z < 8; ++z) v += Sp[(size_t)z * 262144 + f];
  const int e = f & 255, i = (f >> 8) & 63, b = f >> 14;
  const int u = i & 7, m = i >> 3;
  Acat[(size_t)(b*8 + m) * 2304 + 256 + u*256 + e] = f2u(v);
}

// ---------------------------------------------------------------------------
// Level-2 sequential combine: 8 steps, ONE workgroup, split-bf16 MFMA.
// A2_{b,m} (state entering superchunk m) written bf16 into Acat cols 0..255.
// ---------------------------------------------------------------------------
__global__ __launch_bounds__(512, 2) void k4b_combine(
    const unsigned short* __restrict__ LcT2hi, const unsigned short* __restrict__ LcT2lo,
    const float* __restrict__ S2, unsigned short* __restrict__ Acat)
{
  __shared__ unsigned short Hhi[16][264];
  __shared__ unsigned short Hlo[16][264];
  const int tid = threadIdx.x, lane = tid & 63, w = tid >> 6;  // 8 waves
  const int q = lane >> 4, ln = lane & 15;

  v8s bhi[8][2], blo[8][2];                       // (Lam^512)^T frags, cols [32w,32w+32)
#pragma unroll
  for (int kk = 0; kk < 8; ++kk)
#pragma unroll
    for (int nb = 0; nb < 2; ++nb) {
      const int n = 32*w + nb*16 + ln;
#pragma unroll
      for (int r = 0; r < 8; ++r) {
        const int k = kk*32 + q*8 + r;
        bhi[kk][nb][r] = (short)LcT2hi[k*256 + n];
        blo[kk][nb][r] = (short)LcT2lo[k*256 + n];
      }
    }
  for (int e = tid; e < 16*264; e += 512) { (&Hhi[0][0])[e] = 0; (&Hlo[0][0])[e] = 0; }
  lds_barrier();

  for (int m = 0; m < 8; ++m) {
    // A2_{b,m} = state BEFORE absorbing superchunk m
    for (int e = tid; e < 4096; e += 512) {
      const int b = e >> 8, d = e & 255;
      Acat[(size_t)(b*8 + m) * 2304 + d] = Hhi[b][d];
    }
    v8s ahi[8], alo[8];
#pragma unroll
    for (int kk = 0; kk < 8; ++kk) {
      ahi[kk] = *(const v8s*)&Hhi[ln][kk*32 + q*8];
      alo[kk] = *(const v8s*)&Hlo[ln][kk*32 + q*8];
    }
    lds_barrier();
    v4f acc[2];
#pragma unroll
    for (int nb = 0; nb < 2; ++nb)
#pragma unroll
      for (int r = 0; r < 4; ++r) {
        const int bb = 4*q + r, col = 32*w + nb*16 + ln;
        acc[nb][r] = S2[(size_t)(bb*8 + m) * 256 + col];
      }
#pragma unroll
    for (int kk = 0; kk < 8; ++kk)
#pragma unroll
      for (int nb = 0; nb < 2; ++nb) {
        acc[nb] = __builtin_amdgcn_mfma_f32_16x16x32_bf16(ahi[kk], bhi[kk][nb], acc[nb], 0, 0, 0);
        acc[nb] = __builtin_amdgcn_mfma_f32_16x16x32_bf16(alo[kk], bhi[kk][nb], acc[nb], 0, 0, 0);
        acc[nb] = __builtin_amdgcn_mfma_f32_16x16x32_bf16(ahi[kk], blo[kk][nb], acc[nb], 0, 0, 0);
      }
#pragma unroll
    for (int nb = 0; nb < 2; ++nb)
#pragma unroll
      for (int r = 0; r < 4; ++r) {
        const int bb = 4*q + r, col = 32*w + nb*16 + ln;
        float v = acc[nb][r];
        unsigned short hi = f2u(v);
        Hhi[bb][col] = hi;
        Hlo[bb][col] = f2u(v - u2f(hi));
      }
    lds_barrier();
  }
}

// ---------------------------------------------------------------------------
// Phase 3: local scan (init 0), writes g_local (fp32) to Out. Carry added
// later by the carry GEMM's += epilogue. Double-buffered state LDS -> ONE
// lds_barrier per step; Bx depth-2 register prefetch.
// R9: 512 blocks x 2 chunk-states each (was 256 x 4) -> 2 blocks/CU
// co-resident; identical per-chunk operation order (bit-exact).
// ---------------------------------------------------------------------------
__global__ __launch_bounds__(256) void k5_scan(
    const unsigned short* __restrict__ LamT,
    const unsigned short* __restrict__ Bx, float* __restrict__ Out)
{
  __shared__ unsigned short gs[2][16][264];
  const int tid = threadIdx.x, lane = tid & 63, w = tid >> 6;  // 4 waves
  const int q = lane >> 4, ln = lane & 15;
  const int blk = blockIdx.x;          // 0..511
  const int b  = blk >> 5;             // batch 0..15
  const int i0 = (blk * 2) & 63;       // first chunk index (2 chunks/block)

  v8s bf[8][4];                        // Lam^T frags, cols [64w,64w+64)
#pragma unroll
  for (int kk = 0; kk < 8; ++kk)
#pragma unroll
    for (int nb = 0; nb < 4; ++nb) {
      const int n = 64*w + nb*16 + ln;
#pragma unroll
      for (int r = 0; r < 8; ++r)
        bf[kk][nb][r] = (short)LamT[(kk*32 + q*8 + r) * 256 + n];
    }
  for (int e = tid; e < 2*16*264; e += 256) (&gs[0][0][0])[e] = 0;  // zero both bufs

  size_t base[2];
#pragma unroll
  for (int r = 0; r < 2; ++r)
    base[r] = ((size_t)b*4096 + (size_t)(i0 + r)*64) * 256;   // row of step j=0
  const int colw = 64*w;

  unsigned short bxr[2][2][4];         // depth-2 Bx prefetch ring (q==0 lanes)
  if (q == 0) {
#pragma unroll
    for (int s = 0; s < 2; ++s)
#pragma unroll
      for (int r = 0; r < 2; ++r)
#pragma unroll
        for (int nb = 0; nb < 4; ++nb)
          bxr[s][r][nb] = Bx[base[r] + (size_t)s*256 + colw + nb*16 + ln];
  }
  lds_barrier();

#pragma unroll 2
  for (int j = 0; j < CHUNK; ++j) {
    v8s a[8];
#pragma unroll
    for (int kk = 0; kk < 8; ++kk) a[kk] = *(const v8s*)&gs[j & 1][ln][kk*32 + q*8];
    v4f acc[4];
#pragma unroll
    for (int nb = 0; nb < 4; ++nb) acc[nb] = 0;
#pragma unroll
    for (int kk = 0; kk < 8; ++kk)
#pragma unroll
      for (int nb = 0; nb < 4; ++nb)
        acc[nb] = __builtin_amdgcn_mfma_f32_16x16x32_bf16(a[kk], bf[kk][nb], acc[nb], 0, 0, 0);
    if (q == 0) {
#pragma unroll
      for (int r = 0; r < 2; ++r) {
        const size_t rb = base[r] + (size_t)j*256 + colw;
#pragma unroll
        for (int nb = 0; nb < 4; ++nb) {
          const float g = acc[nb][r] + u2f(bxr[j & 1][r][nb]);
          Out[rb + nb*16 + ln] = g;
          gs[(j + 1) & 1][r][colw + nb*16 + ln] = f2u(g);   // write OTHER buffer
        }
      }
      if (j < CHUNK - 2) {
#pragma unroll
        for (int r = 0; r < 2; ++r) {
          const size_t rb = base[r] + (size_t)(j + 2)*256 + colw;
#pragma unroll
          for (int nb = 0; nb < 4; ++nb)
            bxr[j & 1][r][nb] = Bx[rb + nb*16 + ln];
        }
      }
    }
    lds_barrier();   // single barrier: new state visible to all waves
  }
}

// ---------------------------------------------------------------------------
extern "C" void kernel_launch(void* const* d_in, const int* in_sizes, int n_in,
                              void* d_out, int out_size, void* d_ws, size_t ws_size,
                              hipStream_t stream)
{
  const float* x   = (const float*)d_in[0];
  const float* Bm  = (const float*)d_in[1];
  const float* Lam = (const float*)d_in[2];
  float* Out = (float*)d_out;
  (void)in_sizes; (void)n_in; (void)out_size; (void)ws_size;

  char* ws = (char*)d_ws;
  size_t off = 0;
  auto alloc = [&](size_t bytes) { void* p = ws + off; off += (bytes + 255) & ~(size_t)255; return p; };
  unsigned short* Bx    = (unsigned short*)alloc((size_t)16777216 * 2);      // 32 MB
  unsigned short* Phi   = (unsigned short*)alloc((size_t)65 * 65536 * 2);    // 8.3 MB
  unsigned short* Plo   = (unsigned short*)alloc((size_t)65 * 65536 * 2);    // 8.3 MB
  unsigned short* Ghat  = (unsigned short*)alloc((size_t)16384 * 256 * 2);   // 8 MB
  unsigned short* Q     = (unsigned short*)alloc((size_t)256 * 16384 * 2);   // 8 MB
  unsigned short* Qcat  = (unsigned short*)alloc((size_t)2304 * 2048 * 2);   // 9.4 MB
  unsigned short* G2    = (unsigned short*)alloc((size_t)2048 * 256 * 2);    // 1 MB
  unsigned short* Phi2  = (unsigned short*)alloc((size_t)9 * 65536 * 2);
  unsigned short* Plo2  = (unsigned short*)alloc((size_t)9 * 65536 * 2);
  unsigned short* Bt    = (unsigned short*)alloc(131072);
  unsigned short* LamT  = (unsigned short*)alloc(131072);
  unsigned short* LcT2hi= (unsigned short*)alloc(131072);
  unsigned short* LcT2lo= (unsigned short*)alloc(131072);
  unsigned short* Acat  = (unsigned short*)alloc((size_t)128 * 2304 * 2);    // 0.6 MB
  float*          S2    = (float*)alloc(131072);
  unsigned short* Abf   = (unsigned short*)alloc(524288);
  float*          Spart = (float*)Plo;  // alias: Plo dead before summary GEMM writes Spart

  // 1) packs + P0/P1
  pack_init<<<dim3(256), dim3(256), 0, stream>>>(Bm, Lam, Bt, LamT, Phi, Plo);
  // 2) Bx = x @ B^T  (bf16 out)
  gemm_tile<true, true, false><<<dim3(4, 1024, 1), dim3(256), 0, stream>>>(
      (const void*)x, Bt, (void*)Bx, 256, 256, 256, 256, 0);
  // 3) local scans: Out = g_local (fp32). Carry added later by GEMM epilogue.
  k5_scan<<<dim3(512), dim3(256), 0, stream>>>(LamT, Bx, Out);
  // 4) level-1 powers P_2..P_64 by doubling (mp=32 also seeds P2_0/P2_1)
  for (int mp = 1; mp <= 32; mp <<= 1)
    pow_round<<<dim3(mp * 4, 4, 1), dim3(256), 0, stream>>>(Phi, Plo, mp, Phi2, Plo2);
  // 5) level-2 powers P2_2..P2_8
  for (int mp = 1; mp <= 4; mp <<= 1)
    pow_round<<<dim3(mp * 4, 4, 1), dim3(256), 0, stream>>>(Phi2, Plo2, mp, Phi2, Plo2);
  // 6) pack all GEMM operands (fused)
  pack_all<<<dim3(3360), dim3(256), 0, stream>>>(Phi, Phi2, Plo2,
      Ghat, Q, Qcat, G2, LcT2hi, LcT2lo);
  // 7) chunk summaries: S = Bx_reshaped[1024,16384] @ Ghat  (split-K=8)
  gemm_tile<false, false, false><<<dim3(4, 16, 8), dim3(256), 0, stream>>>(
      (const void*)Bx, Ghat, (void*)Spart, 16384, 256, 256, 2048, 262144);
  reduce_s2<<<dim3(1024), dim3(256), 0, stream>>>(Spart, Acat);
  // 8) level-2 summaries: S2[128,256] = Acat_S[128,2048] @ G2
  gemm_tile<false, false, false><<<dim3(4, 2, 1), dim3(256), 0, stream>>>(
      (const void*)(Acat + 256), G2, (void*)S2, 2304, 256, 256, 2048, 0);
  // 9) sequential combine over 8 superchunks -> A2 into Acat cols 0..255
  k4b_combine<<<dim3(1), dim3(512), 0, stream>>>(LcT2hi, LcT2lo, S2, Acat);
  // 10) all chunk-entry states in one GEMM: Abf[128,2048] = Acat[128,2304] @ Qcat
  gemm_tile<false, true, false><<<dim3(32, 2, 1), dim3(256), 0, stream>>>(
      (const void*)Acat, Qcat, (void*)Abf, 2304, 2048, 2048, 2304, 0);
  // 11) carry GEMM with += epilogue: Out = Abf @ Q + Out(g_local)
  gemm_tile<false, false, true><<<dim3(256, 16, 1), dim3(256), 0, stream>>>(
      (const void*)Abf, Q, (void*)Out, 256, 16384, 16384, 256, 0);
}

// Round 8
// 400.607 us; speedup vs baseline: 1.6899x; 1.1527x over previous
//
#include <hip/hip_runtime.h>
#include <hip/hip_bf16.h>
#include <stdint.h>

// Problem: h_t = Lam @ h_{t-1} + B @ x_t ; BS=16, T=4096, D=256, fp32 in/out.
// Two-level chunked scan: level-1 chunks c=64, level-2 superchunks of 8.
// R10:
//  (a) revert R9's scan split (512x2 = 95us, MFMA-issue doubles); back to
//      256 blocks x 4 chunks (65us, verified x3).
//  (b) STRUCTURAL: drop the carry GEMM + Q packing entirely. The scan now
//      runs LAST, initialized with each chunk's entry state A_i (bf16, from
//      Abf) -> h_j = Lam h_{j-1} + bx_j writes final output directly. In a
//      single stream the early-scan+carry-GEMM split bought no overlap and
//      cost ~55-70us (8.6GF + 128MB Out RMW + Q pack). j=0 is bit-identical
//      to the old g+P_1@A; later steps carry the A-term through the same
//      bf16-state rounding the local term already has.

#define CHUNK  64

typedef short v8s __attribute__((ext_vector_type(8)));   // 8 x bf16 (4 VGPRs)
typedef float v4f __attribute__((ext_vector_type(4)));   // MFMA accum

static __device__ __forceinline__ unsigned short f2u(float f) {
  union { float f; unsigned int u; } x; x.f = f;
  unsigned int u = x.u + 0x7FFFu + ((x.u >> 16) & 1u);   // RNE f32->bf16
  return (unsigned short)(u >> 16);
}
static __device__ __forceinline__ float u2f(unsigned short h) {
  union { unsigned int u; float f; } x; x.u = ((unsigned int)h) << 16;
  return x.f;
}
// Workgroup barrier that only drains LDS (lgkmcnt), leaving vmcnt free-running
// so register prefetch loads survive across it.
static __device__ __forceinline__ void lds_barrier() {
  asm volatile("s_waitcnt lgkmcnt(0)\n\ts_barrier" ::: "memory");
}

// ---------------------------------------------------------------------------
// Generic 64x64-tile bf16 MFMA GEMM, depth-1 software-pipelined staging.
// A: f32 or bf16 row-major [M,K] (lda). B: bf16 row-major [K,N] (ldb).
// C: f32 or bf16 [M,N] (ldc). blockIdx = (n_tile, m_tile, k_split).
// Per-split K length = Kper. Split partials go to C + z*csplit (f32 path).
// ADD_C: C += A*B (f32).
// ---------------------------------------------------------------------------
template<bool A_F32, bool C_BF16, bool ADD_C>
__global__ __launch_bounds__(256) void gemm_tile(
    const void* __restrict__ Ap, const unsigned short* __restrict__ Bp,
    void* __restrict__ Cp, int lda, int ldb, int ldc, int Kper, long csplit)
{
  __shared__ unsigned short As[64][72];   // [m][k], pad to kill bank conflicts
  __shared__ unsigned short Bst[64][72];  // [n][k] (transposed for b128 frag reads)
  const int tid = threadIdx.x;
  const int lane = tid & 63, w = tid >> 6;       // 4 waves
  const int q = lane >> 4, ln = lane & 15;
  const long n0 = (long)blockIdx.x * 64;
  const long m0 = (long)blockIdx.y * 64;
  const int  kz = blockIdx.z;
  const long kbase = (long)kz * Kper;
  const int sm = tid >> 2;          // staging row 0..63
  const int sk = (tid & 3) << 4;    // staging col 0,16,32,48

  v4f acc[4];
#pragma unroll
  for (int i = 0; i < 4; ++i) acc[i] = 0;

  // staging registers (next K-tile in flight)
  float4 fA[4];
  v8s aR0, aR1, bR0, bR1;

  auto load_tile = [&](long kg) {
    if (A_F32) {
      const float* A = (const float*)Ap + (m0 + sm) * (long)lda + kg + sk;
#pragma unroll
      for (int t = 0; t < 4; ++t) fA[t] = ((const float4*)A)[t];
    } else {
      const unsigned short* A = (const unsigned short*)Ap + (m0 + sm) * (long)lda + kg + sk;
      aR0 = ((const v8s*)A)[0]; aR1 = ((const v8s*)A)[1];
    }
    const unsigned short* Bg = Bp + (kg + sm) * (long)ldb + n0 + sk;
    bR0 = ((const v8s*)Bg)[0]; bR1 = ((const v8s*)Bg)[1];
  };

  load_tile(kbase);                       // prologue: tile ks=0 in regs

  for (int ks = 0; ks < Kper; ks += 64) {
    __syncthreads();                      // prior MFMA phase done with LDS
    // write staged regs -> LDS
    if (A_F32) {
      unsigned short* d = &As[sm][sk];
#pragma unroll
      for (int t = 0; t < 4; ++t) {
        d[4*t+0] = f2u(fA[t].x); d[4*t+1] = f2u(fA[t].y);
        d[4*t+2] = f2u(fA[t].z); d[4*t+3] = f2u(fA[t].w);
      }
    } else {
      *(v8s*)&As[sm][sk] = aR0; *(v8s*)&As[sm][sk + 8] = aR1;
    }
#pragma unroll
    for (int r = 0; r < 8; ++r) Bst[sk + r][sm] = (unsigned short)bR0[r];
#pragma unroll
    for (int r = 0; r < 8; ++r) Bst[sk + 8 + r][sm] = (unsigned short)bR1[r];
    __syncthreads();
    // prefetch next tile into regs — overlaps with the MFMA phase below
    if (ks + 64 < Kper) load_tile(kbase + ks + 64);
#pragma unroll
    for (int kb = 0; kb < 64; kb += 32) {
      v8s a = *(const v8s*)&As[w*16 + ln][kb + q*8];
#pragma unroll
      for (int nb = 0; nb < 4; ++nb) {
        v8s b = *(const v8s*)&Bst[nb*16 + ln][kb + q*8];
        acc[nb] = __builtin_amdgcn_mfma_f32_16x16x32_bf16(a, b, acc[nb], 0, 0, 0);
      }
    }
  }
#pragma unroll
  for (int nb = 0; nb < 4; ++nb)
#pragma unroll
    for (int r = 0; r < 4; ++r) {
      const long row = m0 + w*16 + q*4 + r;        // D row = 4q+r within wave's 16
      const long col = n0 + nb*16 + ln;
      float v = acc[nb][r];
      if (C_BF16) ((unsigned short*)Cp)[row * (long)ldc + col] = f2u(v);
      else {
        float* Cf = (float*)Cp + (long)kz * csplit;
        if (ADD_C) v += Cf[row * (long)ldc + col];
        Cf[row * (long)ldc + col] = v;
      }
    }
}

// ---------------------------------------------------------------------------
// Powers by doubling, split-bf16 (hi+lo): P_{mpow+jj} = P_mpow * P_jj,
// jj=1..mpow.  acc = Ah*Bh + Al*Bh + Ah*Bl (drops lo*lo) -> ~fp32.
// Depth-1 pipelined over the flattened 12-iteration (seg,ks) loop.
// Fused pack2 init: at mpow==32, jj==32 blocks also write P2_1 = P_64 (hi/lo)
// and jj==1 blocks write P2_0 = I.
// ---------------------------------------------------------------------------
__global__ __launch_bounds__(256) void pow_round(
    unsigned short* __restrict__ Phi, unsigned short* __restrict__ Plo, int mpow,
    unsigned short* __restrict__ Phi2, unsigned short* __restrict__ Plo2)
{
  __shared__ unsigned short As[64][72];
  __shared__ unsigned short Bst[64][72];
  const int tid = threadIdx.x, lane = tid & 63, w = tid >> 6;
  const int q = lane >> 4, ln = lane & 15;
  const int jj = (blockIdx.x >> 2) + 1;
  const int n0 = (blockIdx.x & 3) * 64;
  const int m0 = blockIdx.y * 64;
  const unsigned short* Ah = Phi + (size_t)mpow * 65536;
  const unsigned short* Al = Plo + (size_t)mpow * 65536;
  const unsigned short* Bh = Phi + (size_t)jj * 65536;
  const unsigned short* Bl = Plo + (size_t)jj * 65536;
  const int sm = tid >> 2, sk = (tid & 3) << 4;
  v4f acc[4];
#pragma unroll
  for (int i = 0; i < 4; ++i) acc[i] = 0;

  v8s aR0, aR1, bR0, bR1;
  auto load_tile = [&](int it) {
    const int seg = it >> 2, ks = (it & 3) << 6;
    const unsigned short* Asrc = (seg == 1) ? Al : Ah;
    const unsigned short* Bsrc = (seg == 2) ? Bl : Bh;
    const unsigned short* Ag = Asrc + (size_t)(m0 + sm) * 256 + ks + sk;
    aR0 = ((const v8s*)Ag)[0]; aR1 = ((const v8s*)Ag)[1];
    const unsigned short* Bg = Bsrc + (size_t)(ks + sm) * 256 + n0 + sk;
    bR0 = ((const v8s*)Bg)[0]; bR1 = ((const v8s*)Bg)[1];
  };

  load_tile(0);
  for (int it = 0; it < 12; ++it) {
    __syncthreads();
    *(v8s*)&As[sm][sk] = aR0; *(v8s*)&As[sm][sk + 8] = aR1;
#pragma unroll
    for (int r = 0; r < 8; ++r) Bst[sk + r][sm] = (unsigned short)bR0[r];
#pragma unroll
    for (int r = 0; r < 8; ++r) Bst[sk + 8 + r][sm] = (unsigned short)bR1[r];
    __syncthreads();
    if (it + 1 < 12) load_tile(it + 1);   // overlaps with MFMA below
#pragma unroll
    for (int kb = 0; kb < 64; kb += 32) {
      v8s a = *(const v8s*)&As[w*16 + ln][kb + q*8];
#pragma unroll
      for (int nb = 0; nb < 4; ++nb) {
        v8s bb = *(const v8s*)&Bst[nb*16 + ln][kb + q*8];
        acc[nb] = __builtin_amdgcn_mfma_f32_16x16x32_bf16(a, bb, acc[nb], 0, 0, 0);
      }
    }
  }
  const size_t ob = (size_t)(mpow + jj) * 65536;
#pragma unroll
  for (int nb = 0; nb < 4; ++nb)
#pragma unroll
    for (int r = 0; r < 4; ++r) {
      const int row = m0 + w*16 + q*4 + r;
      const int col = n0 + nb*16 + ln;
      float v = acc[nb][r];
      unsigned short hi = f2u(v);
      Phi[ob + (size_t)row*256 + col] = hi;
      Plo[ob + (size_t)row*256 + col] = f2u(v - u2f(hi));
      if (mpow == 32) {                       // fused pack2 init
        if (jj == 32) {                       // P2_1 = P_64 (this result)
          Phi2[65536 + (size_t)row*256 + col] = hi;
          Plo2[65536 + (size_t)row*256 + col] = f2u(v - u2f(hi));
        } else if (jj == 1) {                 // P2_0 = I (tile m0,n0)
          Phi2[(size_t)row*256 + col] = (row == col) ? (unsigned short)0x3F80 : (unsigned short)0;
          Plo2[(size_t)row*256 + col] = 0;
        }
      }
    }
}

// ---------------------------------------------------------------------------
// pack_init: Bt[e][d]=B[d][e], LamT[e][d]=Lam[d][e] (bf16); P_0=I, P_1=Lam hi/lo.
// ---------------------------------------------------------------------------
__global__ __launch_bounds__(256) void pack_init(
    const float* __restrict__ Bm, const float* __restrict__ Lam,
    unsigned short* __restrict__ Bt, unsigned short* __restrict__ LamT,
    unsigned short* __restrict__ Phi, unsigned short* __restrict__ Plo)
{
  const int idx = blockIdx.x * 256 + threadIdx.x;  // 0..65535
  const int e = idx >> 8, d = idx & 255;
  Bt[idx]   = f2u(Bm[d * 256 + e]);
  LamT[idx] = f2u(Lam[d * 256 + e]);
  float v = Lam[idx];                              // idx as (dd,ee) row-major
  unsigned short hi = f2u(v);
  Phi[65536 + idx] = hi;
  Plo[65536 + idx] = f2u(v - u2f(hi));
  const int dd = idx >> 8, ee = idx & 255;
  Phi[idx] = (dd == ee) ? (unsigned short)0x3F80 : (unsigned short)0;
  Plo[idx] = 0;
}

// ---------------------------------------------------------------------------
// pack_all: Ghat (blocks 0..1023) + Qcat/G2/LcT2 (blocks 1024..2335).
//  Ghat[(j*256+e)][d] = P_{63-j}[d][e]
//  Qcat[2304][2048], G2[2048][256], LcT2hi/lo[e][d] = P2_8[d][e]
// (Q dropped in R10 — carry GEMM eliminated.)
// ---------------------------------------------------------------------------
__global__ __launch_bounds__(256) void pack_all(
    const unsigned short* __restrict__ Phi,
    const unsigned short* __restrict__ Phi2, const unsigned short* __restrict__ Plo2,
    unsigned short* __restrict__ Ghat,
    unsigned short* __restrict__ Qcat, unsigned short* __restrict__ G2,
    unsigned short* __restrict__ LcT2hi, unsigned short* __restrict__ LcT2lo)
{
  __shared__ unsigned short tile[64][65];
  const int tx = threadIdx.x & 63, ty = threadIdx.x >> 6;  // ty 0..3
  const int blk0 = blockIdx.x;
  if (blk0 < 1024) {
    const int jpar = blk0 >> 4, t16 = blk0 & 15;
    const unsigned short* src = Phi + (size_t)(63 - jpar) * 65536;
    const int d0 = (t16 & 3) * 64, e0 = (t16 >> 2) * 64;
#pragma unroll
    for (int s = 0; s < 16; ++s)
      tile[ty*16 + s][tx] = src[(size_t)(d0 + ty*16 + s) * 256 + e0 + tx];
    __syncthreads();
#pragma unroll
    for (int s = 0; s < 16; ++s) {
      const int e = e0 + ty*16 + s, d = d0 + tx;
      Ghat[((size_t)(jpar*256 + e)) * 256 + d] = tile[tx][ty*16 + s];
    }
    return;
  }
  const int blk = blk0 - 1024;
  if (blk < 1152) {                                  // Qcat: 36x32 tiles of 64x64
    const int rt = blk >> 5, ct = blk & 31;
    const int k0 = rt * 64, c0 = ct * 64;
    const int r = c0 >> 8, d0 = c0 & 255;
    int p = 0, e0 = 0;
    bool zero = false;
    if (k0 < 256) { p = r; e0 = k0; }
    else {
      const int u = (k0 - 256) >> 8; e0 = (k0 - 256) & 255;
      if (u >= r) zero = true; else p = r - 1 - u;
    }
    if (zero) {
#pragma unroll
      for (int s = 0; s < 16; ++s)
        Qcat[(size_t)(k0 + ty*16 + s) * 2048 + c0 + tx] = 0;
      return;
    }
    const unsigned short* src = Phi2 + (size_t)p * 65536;
#pragma unroll
    for (int s = 0; s < 16; ++s)
      tile[ty*16 + s][tx] = src[(size_t)(d0 + ty*16 + s) * 256 + e0 + tx];
    __syncthreads();
#pragma unroll
    for (int s = 0; s < 16; ++s)
      Qcat[(size_t)(k0 + ty*16 + s) * 2048 + c0 + tx] = tile[tx][ty*16 + s];
  } else if (blk < 1280) {                           // G2: 32x4 tiles
    const int t = blk - 1152;
    const int rt = t >> 2, ct = t & 3;
    const int k0 = rt * 64, d0 = ct * 64;
    const int r = k0 >> 8, e0 = k0 & 255;
    const unsigned short* src = Phi2 + (size_t)(7 - r) * 65536;
#pragma unroll
    for (int s = 0; s < 16; ++s)
      tile[ty*16 + s][tx] = src[(size_t)(d0 + ty*16 + s) * 256 + e0 + tx];
    __syncthreads();
#pragma unroll
    for (int s = 0; s < 16; ++s)
      G2[(size_t)(k0 + ty*16 + s) * 256 + d0 + tx] = tile[tx][ty*16 + s];
  } else {                                           // LcT2 hi (16) + lo (16)
    const int t = blk - 1280;
    const int half = t >> 4, t16 = t & 15;
    const int d0 = (t16 & 3) * 64, e0 = (t16 >> 2) * 64;
    const unsigned short* src = (half ? Plo2 : Phi2) + (size_t)8 * 65536;
    unsigned short* dst = half ? LcT2lo : LcT2hi;
#pragma unroll
    for (int s = 0; s < 16; ++s)
      tile[ty*16 + s][tx] = src[(size_t)(d0 + ty*16 + s) * 256 + e0 + tx];
    __syncthreads();
#pragma unroll
    for (int s = 0; s < 16; ++s)
      dst[(size_t)(e0 + ty*16 + s) * 256 + d0 + tx] = tile[tx][ty*16 + s];
  }
}

// ---------------------------------------------------------------------------
// reduce split-K partials and scatter into Acat (bf16) S-region:
// s_{b, i=8m+u}[e] -> Acat[b*8+m][256 + u*256 + e]
// ---------------------------------------------------------------------------
__global__ __launch_bounds__(256) void reduce_s2(
    const float* __restrict__ Sp, unsigned short* __restrict__ Acat)
{
  const int f = blockIdx.x * 256 + threadIdx.x;   // 262144 total
  float v = 0;
#pragma unroll
  for (int z = 0; z < 8; ++z) v += Sp[(size_t)z * 262144 + f];
  const int e = f & 255, i = (f >> 8) & 63, b = f >> 14;
  const int u = i & 7, m = i >> 3;
  Acat[(size_t)(b*8 + m) * 2304 + 256 + u*256 + e] = f2u(v);
}

// ---------------------------------------------------------------------------
// Level-2 sequential combine: 8 steps, ONE workgroup, split-bf16 MFMA.
// A2_{b,m} (state entering superchunk m) written bf16 into Acat cols 0..255.
// ---------------------------------------------------------------------------
__global__ __launch_bounds__(512, 2) void k4b_combine(
    const unsigned short* __restrict__ LcT2hi, const unsigned short* __restrict__ LcT2lo,
    const float* __restrict__ S2, unsigned short* __restrict__ Acat)
{
  __shared__ unsigned short Hhi[16][264];
  __shared__ unsigned short Hlo[16][264];
  const int tid = threadIdx.x, lane = tid & 63, w = tid >> 6;  // 8 waves
  const int q = lane >> 4, ln = lane & 15;

  v8s bhi[8][2], blo[8][2];                       // (Lam^512)^T frags, cols [32w,32w+32)
#pragma unroll
  for (int kk = 0; kk < 8; ++kk)
#pragma unroll
    for (int nb = 0; nb < 2; ++nb) {
      const int n = 32*w + nb*16 + ln;
#pragma unroll
      for (int r = 0; r < 8; ++r) {
        const int k = kk*32 + q*8 + r;
        bhi[kk][nb][r] = (short)LcT2hi[k*256 + n];
        blo[kk][nb][r] = (short)LcT2lo[k*256 + n];
      }
    }
  for (int e = tid; e < 16*264; e += 512) { (&Hhi[0][0])[e] = 0; (&Hlo[0][0])[e] = 0; }
  lds_barrier();

  for (int m = 0; m < 8; ++m) {
    // A2_{b,m} = state BEFORE absorbing superchunk m
    for (int e = tid; e < 4096; e += 512) {
      const int b = e >> 8, d = e & 255;
      Acat[(size_t)(b*8 + m) * 2304 + d] = Hhi[b][d];
    }
    v8s ahi[8], alo[8];
#pragma unroll
    for (int kk = 0; kk < 8; ++kk) {
      ahi[kk] = *(const v8s*)&Hhi[ln][kk*32 + q*8];
      alo[kk] = *(const v8s*)&Hlo[ln][kk*32 + q*8];
    }
    lds_barrier();
    v4f acc[2];
#pragma unroll
    for (int nb = 0; nb < 2; ++nb)
#pragma unroll
      for (int r = 0; r < 4; ++r) {
        const int bb = 4*q + r, col = 32*w + nb*16 + ln;
        acc[nb][r] = S2[(size_t)(bb*8 + m) * 256 + col];
      }
#pragma unroll
    for (int kk = 0; kk < 8; ++kk)
#pragma unroll
      for (int nb = 0; nb < 2; ++nb) {
        acc[nb] = __builtin_amdgcn_mfma_f32_16x16x32_bf16(ahi[kk], bhi[kk][nb], acc[nb], 0, 0, 0);
        acc[nb] = __builtin_amdgcn_mfma_f32_16x16x32_bf16(alo[kk], bhi[kk][nb], acc[nb], 0, 0, 0);
        acc[nb] = __builtin_amdgcn_mfma_f32_16x16x32_bf16(ahi[kk], blo[kk][nb], acc[nb], 0, 0, 0);
      }
#pragma unroll
    for (int nb = 0; nb < 2; ++nb)
#pragma unroll
      for (int r = 0; r < 4; ++r) {
        const int bb = 4*q + r, col = 32*w + nb*16 + ln;
        float v = acc[nb][r];
        unsigned short hi = f2u(v);
        Hhi[bb][col] = hi;
        Hlo[bb][col] = f2u(v - u2f(hi));
      }
    lds_barrier();
  }
}

// ---------------------------------------------------------------------------
// Final scan: state initialized from Abf (chunk-entry states, bf16) ->
// h_j = Lam h_{j-1} + bx_j writes the FINAL output. Runs last.
// 256 blocks x 4 chunk-states, double-buffered gs, ONE lds_barrier/step,
// Bx depth-2 register prefetch. Abf viewed [1024][256]: row = b*64 + i.
// ---------------------------------------------------------------------------
__global__ __launch_bounds__(256, 1) void k5_scan(
    const unsigned short* __restrict__ LamT,
    const unsigned short* __restrict__ Bx,
    const unsigned short* __restrict__ Abf, float* __restrict__ Out)
{
  __shared__ unsigned short gs[2][16][264];
  const int tid = threadIdx.x, lane = tid & 63, w = tid >> 6;  // 4 waves
  const int q = lane >> 4, ln = lane & 15;
  const int blk = blockIdx.x;
  const int b  = blk >> 4;            // batch
  const int i0 = (blk * 4) & 63;      // first chunk index of this block

  v8s bf[8][4];                        // Lam^T frags, cols [64w,64w+64)
#pragma unroll
  for (int kk = 0; kk < 8; ++kk)
#pragma unroll
    for (int nb = 0; nb < 4; ++nb) {
      const int n = 64*w + nb*16 + ln;
#pragma unroll
      for (int r = 0; r < 8; ++r)
        bf[kk][nb][r] = (short)LamT[(kk*32 + q*8 + r) * 256 + n];
    }
  for (int e = tid; e < 16*264; e += 256) (&gs[0][0][0])[e] = 0;  // zero buf 0
  lds_barrier();
  // init rows 0..3 of buf 0 with chunk-entry states A_{b,i0+r}
#pragma unroll
  for (int r = 0; r < 4; ++r)
    gs[0][r][tid] = Abf[((size_t)(b*64 + i0 + r)) * 256 + tid];

  size_t base[4];
#pragma unroll
  for (int r = 0; r < 4; ++r)
    base[r] = ((size_t)b*4096 + (size_t)(i0 + r)*64) * 256;   // row of step j=0
  const int colw = 64*w;

  unsigned short bxr[2][4][4];         // depth-2 Bx prefetch ring (q==0 lanes)
  if (q == 0) {
#pragma unroll
    for (int s = 0; s < 2; ++s)
#pragma unroll
      for (int r = 0; r < 4; ++r)
#pragma unroll
        for (int nb = 0; nb < 4; ++nb)
          bxr[s][r][nb] = Bx[base[r] + (size_t)s*256 + colw + nb*16 + ln];
  }
  lds_barrier();

#pragma unroll 2
  for (int j = 0; j < CHUNK; ++j) {
    v8s a[8];
#pragma unroll
    for (int kk = 0; kk < 8; ++kk) a[kk] = *(const v8s*)&gs[j & 1][ln][kk*32 + q*8];
    v4f acc[4];
#pragma unroll
    for (int nb = 0; nb < 4; ++nb) acc[nb] = 0;
#pragma unroll
    for (int kk = 0; kk < 8; ++kk)
#pragma unroll
      for (int nb = 0; nb < 4; ++nb)
        acc[nb] = __builtin_amdgcn_mfma_f32_16x16x32_bf16(a[kk], bf[kk][nb], acc[nb], 0, 0, 0);
    if (q == 0) {
#pragma unroll
      for (int r = 0; r < 4; ++r) {
        const size_t rb = base[r] + (size_t)j*256 + colw;
#pragma unroll
        for (int nb = 0; nb < 4; ++nb) {
          const float g = acc[nb][r] + u2f(bxr[j & 1][r][nb]);
          Out[rb + nb*16 + ln] = g;                          // FINAL h
          gs[(j + 1) & 1][r][colw + nb*16 + ln] = f2u(g);    // write OTHER buffer
        }
      }
      if (j < CHUNK - 2) {
#pragma unroll
        for (int r = 0; r < 4; ++r) {
          const size_t rb = base[r] + (size_t)(j + 2)*256 + colw;
#pragma unroll
          for (int nb = 0; nb < 4; ++nb)
            bxr[j & 1][r][nb] = Bx[rb + nb*16 + ln];
        }
      }
    }
    lds_barrier();   // single barrier: new state visible to all waves
  }
}

// ---------------------------------------------------------------------------
extern "C" void kernel_launch(void* const* d_in, const int* in_sizes, int n_in,
                              void* d_out, int out_size, void* d_ws, size_t ws_size,
                              hipStream_t stream)
{
  const float* x   = (const float*)d_in[0];
  const float* Bm  = (const float*)d_in[1];
  const float* Lam = (const float*)d_in[2];
  float* Out = (float*)d_out;
  (void)in_sizes; (void)n_in; (void)out_size; (void)ws_size;

  char* ws = (char*)d_ws;
  size_t off = 0;
  auto alloc = [&](size_t bytes) { void* p = ws + off; off += (bytes + 255) & ~(size_t)255; return p; };
  unsigned short* Bx    = (unsigned short*)alloc((size_t)16777216 * 2);      // 32 MB
  unsigned short* Phi   = (unsigned short*)alloc((size_t)65 * 65536 * 2);    // 8.3 MB
  unsigned short* Plo   = (unsigned short*)alloc((size_t)65 * 65536 * 2);    // 8.3 MB
  unsigned short* Ghat  = (unsigned short*)alloc((size_t)16384 * 256 * 2);   // 8 MB
  unsigned short* Qcat  = (unsigned short*)alloc((size_t)2304 * 2048 * 2);   // 9.4 MB
  unsigned short* G2    = (unsigned short*)alloc((size_t)2048 * 256 * 2);    // 1 MB
  unsigned short* Phi2  = (unsigned short*)alloc((size_t)9 * 65536 * 2);
  unsigned short* Plo2  = (unsigned short*)alloc((size_t)9 * 65536 * 2);
  unsigned short* Bt    = (unsigned short*)alloc(131072);
  unsigned short* LamT  = (unsigned short*)alloc(131072);
  unsigned short* LcT2hi= (unsigned short*)alloc(131072);
  unsigned short* LcT2lo= (unsigned short*)alloc(131072);
  unsigned short* Acat  = (unsigned short*)alloc((size_t)128 * 2304 * 2);    // 0.6 MB
  float*          S2    = (float*)alloc(131072);
  unsigned short* Abf   = (unsigned short*)alloc(524288);
  float*          Spart = (float*)Plo;  // alias: Plo dead before summary GEMM writes Spart

  // 1) packs + P0/P1
  pack_init<<<dim3(256), dim3(256), 0, stream>>>(Bm, Lam, Bt, LamT, Phi, Plo);
  // 2) Bx = x @ B^T  (bf16 out)
  gemm_tile<true, true, false><<<dim3(4, 1024, 1), dim3(256), 0, stream>>>(
      (const void*)x, Bt, (void*)Bx, 256, 256, 256, 256, 0);
  // 3) level-1 powers P_2..P_64 by doubling (mp=32 also seeds P2_0/P2_1)
  for (int mp = 1; mp <= 32; mp <<= 1)
    pow_round<<<dim3(mp * 4, 4, 1), dim3(256), 0, stream>>>(Phi, Plo, mp, Phi2, Plo2);
  // 4) level-2 powers P2_2..P2_8
  for (int mp = 1; mp <= 4; mp <<= 1)
    pow_round<<<dim3(mp * 4, 4, 1), dim3(256), 0, stream>>>(Phi2, Plo2, mp, Phi2, Plo2);
  // 5) pack GEMM operands (Ghat, Qcat, G2, LcT2)
  pack_all<<<dim3(2336), dim3(256), 0, stream>>>(Phi, Phi2, Plo2,
      Ghat, Qcat, G2, LcT2hi, LcT2lo);
  // 6) chunk summaries: S = Bx_reshaped[1024,16384] @ Ghat  (split-K=8)
  gemm_tile<false, false, false><<<dim3(4, 16, 8), dim3(256), 0, stream>>>(
      (const void*)Bx, Ghat, (void*)Spart, 16384, 256, 256, 2048, 262144);
  reduce_s2<<<dim3(1024), dim3(256), 0, stream>>>(Spart, Acat);
  // 7) level-2 summaries: S2[128,256] = Acat_S[128,2048] @ G2
  gemm_tile<false, false, false><<<dim3(4, 2, 1), dim3(256), 0, stream>>>(
      (const void*)(Acat + 256), G2, (void*)S2, 2304, 256, 256, 2048, 0);
  // 8) sequential combine over 8 superchunks -> A2 into Acat cols 0..255
  k4b_combine<<<dim3(1), dim3(512), 0, stream>>>(LcT2hi, LcT2lo, S2, Acat);
  // 9) all chunk-entry states: Abf[128,2048] = Acat[128,2304] @ Qcat
  gemm_tile<false, true, false><<<dim3(32, 2, 1), dim3(256), 0, stream>>>(
      (const void*)Acat, Qcat, (void*)Abf, 2304, 2048, 2048, 2304, 0);
  // 10) FINAL scan with chunk-entry init: Out = full h (no carry GEMM)
  k5_scan<<<dim3(256), dim3(256), 0, stream>>>(LamT, Bx, Abf, Out);
}

// Round 9
// 366.912 us; speedup vs baseline: 1.8451x; 1.0918x over previous
//
#include <hip/hip_runtime.h>
#include <hip/hip_bf16.h>
#include <stdint.h>

// Problem: h_t = Lam @ h_{t-1} + B @ x_t ; BS=16, T=4096, D=256, fp32 in/out.
// Two-level chunked scan: level-1 chunks c=64, level-2 superchunks of 8.
// R11 (from R10's 400us, absmax 5.5):
//  (a) k5_scan: chunk c state moved to gs row 4c -> MFMA D row 4c lands in
//      lane-group q=c -> epilogue (Out store + LDS write + Bx prefetch)
//      spread over ALL 64 lanes (4 ops/lane, was 16 ops on 16 lanes).
//      Matrix rows independent + same K order => bit-identical output.
//  (b) pow_round: 512 threads, 128-wide K staging -> 6 serial staged iters
//      (was 12), 8 waves/block. Same K accumulation order => bit-identical.

#define CHUNK  64

typedef short v8s __attribute__((ext_vector_type(8)));   // 8 x bf16 (4 VGPRs)
typedef float v4f __attribute__((ext_vector_type(4)));   // MFMA accum

static __device__ __forceinline__ unsigned short f2u(float f) {
  union { float f; unsigned int u; } x; x.f = f;
  unsigned int u = x.u + 0x7FFFu + ((x.u >> 16) & 1u);   // RNE f32->bf16
  return (unsigned short)(u >> 16);
}
static __device__ __forceinline__ float u2f(unsigned short h) {
  union { unsigned int u; float f; } x; x.u = ((unsigned int)h) << 16;
  return x.f;
}
// Workgroup barrier that only drains LDS (lgkmcnt), leaving vmcnt free-running
// so register prefetch loads survive across it.
static __device__ __forceinline__ void lds_barrier() {
  asm volatile("s_waitcnt lgkmcnt(0)\n\ts_barrier" ::: "memory");
}

// ---------------------------------------------------------------------------
// Generic 64x64-tile bf16 MFMA GEMM, depth-1 software-pipelined staging.
// A: f32 or bf16 row-major [M,K] (lda). B: bf16 row-major [K,N] (ldb).
// C: f32 or bf16 [M,N] (ldc). blockIdx = (n_tile, m_tile, k_split).
// Per-split K length = Kper. Split partials go to C + z*csplit (f32 path).
// ADD_C: C += A*B (f32).
// ---------------------------------------------------------------------------
template<bool A_F32, bool C_BF16, bool ADD_C>
__global__ __launch_bounds__(256) void gemm_tile(
    const void* __restrict__ Ap, const unsigned short* __restrict__ Bp,
    void* __restrict__ Cp, int lda, int ldb, int ldc, int Kper, long csplit)
{
  __shared__ unsigned short As[64][72];   // [m][k], pad to kill bank conflicts
  __shared__ unsigned short Bst[64][72];  // [n][k] (transposed for b128 frag reads)
  const int tid = threadIdx.x;
  const int lane = tid & 63, w = tid >> 6;       // 4 waves
  const int q = lane >> 4, ln = lane & 15;
  const long n0 = (long)blockIdx.x * 64;
  const long m0 = (long)blockIdx.y * 64;
  const int  kz = blockIdx.z;
  const long kbase = (long)kz * Kper;
  const int sm = tid >> 2;          // staging row 0..63
  const int sk = (tid & 3) << 4;    // staging col 0,16,32,48

  v4f acc[4];
#pragma unroll
  for (int i = 0; i < 4; ++i) acc[i] = 0;

  // staging registers (next K-tile in flight)
  float4 fA[4];
  v8s aR0, aR1, bR0, bR1;

  auto load_tile = [&](long kg) {
    if (A_F32) {
      const float* A = (const float*)Ap + (m0 + sm) * (long)lda + kg + sk;
#pragma unroll
      for (int t = 0; t < 4; ++t) fA[t] = ((const float4*)A)[t];
    } else {
      const unsigned short* A = (const unsigned short*)Ap + (m0 + sm) * (long)lda + kg + sk;
      aR0 = ((const v8s*)A)[0]; aR1 = ((const v8s*)A)[1];
    }
    const unsigned short* Bg = Bp + (kg + sm) * (long)ldb + n0 + sk;
    bR0 = ((const v8s*)Bg)[0]; bR1 = ((const v8s*)Bg)[1];
  };

  load_tile(kbase);                       // prologue: tile ks=0 in regs

  for (int ks = 0; ks < Kper; ks += 64) {
    __syncthreads();                      // prior MFMA phase done with LDS
    // write staged regs -> LDS
    if (A_F32) {
      unsigned short* d = &As[sm][sk];
#pragma unroll
      for (int t = 0; t < 4; ++t) {
        d[4*t+0] = f2u(fA[t].x); d[4*t+1] = f2u(fA[t].y);
        d[4*t+2] = f2u(fA[t].z); d[4*t+3] = f2u(fA[t].w);
      }
    } else {
      *(v8s*)&As[sm][sk] = aR0; *(v8s*)&As[sm][sk + 8] = aR1;
    }
#pragma unroll
    for (int r = 0; r < 8; ++r) Bst[sk + r][sm] = (unsigned short)bR0[r];
#pragma unroll
    for (int r = 0; r < 8; ++r) Bst[sk + 8 + r][sm] = (unsigned short)bR1[r];
    __syncthreads();
    // prefetch next tile into regs — overlaps with the MFMA phase below
    if (ks + 64 < Kper) load_tile(kbase + ks + 64);
#pragma unroll
    for (int kb = 0; kb < 64; kb += 32) {
      v8s a = *(const v8s*)&As[w*16 + ln][kb + q*8];
#pragma unroll
      for (int nb = 0; nb < 4; ++nb) {
        v8s b = *(const v8s*)&Bst[nb*16 + ln][kb + q*8];
        acc[nb] = __builtin_amdgcn_mfma_f32_16x16x32_bf16(a, b, acc[nb], 0, 0, 0);
      }
    }
  }
#pragma unroll
  for (int nb = 0; nb < 4; ++nb)
#pragma unroll
    for (int r = 0; r < 4; ++r) {
      const long row = m0 + w*16 + q*4 + r;        // D row = 4q+r within wave's 16
      const long col = n0 + nb*16 + ln;
      float v = acc[nb][r];
      if (C_BF16) ((unsigned short*)Cp)[row * (long)ldc + col] = f2u(v);
      else {
        float* Cf = (float*)Cp + (long)kz * csplit;
        if (ADD_C) v += Cf[row * (long)ldc + col];
        Cf[row * (long)ldc + col] = v;
      }
    }
}

// ---------------------------------------------------------------------------
// Powers by doubling, split-bf16 (hi+lo): P_{mpow+jj} = P_mpow * P_jj,
// jj=1..mpow.  acc = Ah*Bh + Al*Bh + Ah*Bl (drops lo*lo) -> ~fp32.
// R11: 512 threads, 128-wide K staging -> 6 staged iters (was 12 at 64-wide);
// same K accumulation order (0,32,...,224 per segment) => bit-identical.
// 8 waves: wave w -> m-block mb=w>>1 (16 rows), n-half nh=w&1 (32 cols).
// Fused pack2 init: at mpow==32, jj==32 blocks also write P2_1 = P_64 (hi/lo)
// and jj==1 blocks write P2_0 = I.
// ---------------------------------------------------------------------------
__global__ __launch_bounds__(512) void pow_round(
    unsigned short* __restrict__ Phi, unsigned short* __restrict__ Plo, int mpow,
    unsigned short* __restrict__ Phi2, unsigned short* __restrict__ Plo2)
{
  __shared__ unsigned short As[64][136];
  __shared__ unsigned short Bst[64][136];
  const int tid = threadIdx.x, lane = tid & 63, w = tid >> 6;  // 8 waves
  const int q = lane >> 4, ln = lane & 15;
  const int jj = (blockIdx.x >> 2) + 1;
  const int n0 = (blockIdx.x & 3) * 64;
  const int m0 = blockIdx.y * 64;
  const int mb = w >> 1, nh = w & 1;     // wave's m-block / n-half
  const unsigned short* Ah = Phi + (size_t)mpow * 65536;
  const unsigned short* Al = Plo + (size_t)mpow * 65536;
  const unsigned short* Bh = Phi + (size_t)jj * 65536;
  const unsigned short* Bl = Plo + (size_t)jj * 65536;
  const int sm  = tid >> 3, sk  = (tid & 7) << 4;   // A staging: row 0..63, col 0..112
  const int smk = tid >> 2, snk = (tid & 3) << 4;   // B staging: k-row 0..127, n 0..48
  v4f acc[2];
#pragma unroll
  for (int i = 0; i < 2; ++i) acc[i] = 0;

  v8s aR0, aR1, bR0, bR1;
  auto load_tile = [&](int it) {
    const int seg = it >> 1, ks = (it & 1) << 7;    // seg 0..2, ks 0/128
    const unsigned short* Asrc = (seg == 1) ? Al : Ah;
    const unsigned short* Bsrc = (seg == 2) ? Bl : Bh;
    const unsigned short* Ag = Asrc + (size_t)(m0 + sm) * 256 + ks + sk;
    aR0 = ((const v8s*)Ag)[0]; aR1 = ((const v8s*)Ag)[1];
    const unsigned short* Bg = Bsrc + (size_t)(ks + smk) * 256 + n0 + snk;
    bR0 = ((const v8s*)Bg)[0]; bR1 = ((const v8s*)Bg)[1];
  };

  load_tile(0);
  for (int it = 0; it < 6; ++it) {
    __syncthreads();
    *(v8s*)&As[sm][sk] = aR0; *(v8s*)&As[sm][sk + 8] = aR1;
#pragma unroll
    for (int r = 0; r < 8; ++r) Bst[snk + r][smk] = (unsigned short)bR0[r];
#pragma unroll
    for (int r = 0; r < 8; ++r) Bst[snk + 8 + r][smk] = (unsigned short)bR1[r];
    __syncthreads();
    if (it + 1 < 6) load_tile(it + 1);   // overlaps with MFMA below
#pragma unroll
    for (int kb = 0; kb < 128; kb += 32) {
      v8s a = *(const v8s*)&As[mb*16 + ln][kb + q*8];
#pragma unroll
      for (int nb = 0; nb < 2; ++nb) {
        v8s bb = *(const v8s*)&Bst[nh*32 + nb*16 + ln][kb + q*8];
        acc[nb] = __builtin_amdgcn_mfma_f32_16x16x32_bf16(a, bb, acc[nb], 0, 0, 0);
      }
    }
  }
  const size_t ob = (size_t)(mpow + jj) * 65536;
#pragma unroll
  for (int nb = 0; nb < 2; ++nb)
#pragma unroll
    for (int r = 0; r < 4; ++r) {
      const int row = m0 + mb*16 + q*4 + r;
      const int col = n0 + nh*32 + nb*16 + ln;
      float v = acc[nb][r];
      unsigned short hi = f2u(v);
      Phi[ob + (size_t)row*256 + col] = hi;
      Plo[ob + (size_t)row*256 + col] = f2u(v - u2f(hi));
      if (mpow == 32) {                       // fused pack2 init
        if (jj == 32) {                       // P2_1 = P_64 (this result)
          Phi2[65536 + (size_t)row*256 + col] = hi;
          Plo2[65536 + (size_t)row*256 + col] = f2u(v - u2f(hi));
        } else if (jj == 1) {                 // P2_0 = I (tile m0,n0)
          Phi2[(size_t)row*256 + col] = (row == col) ? (unsigned short)0x3F80 : (unsigned short)0;
          Plo2[(size_t)row*256 + col] = 0;
        }
      }
    }
}

// ---------------------------------------------------------------------------
// pack_init: Bt[e][d]=B[d][e], LamT[e][d]=Lam[d][e] (bf16); P_0=I, P_1=Lam hi/lo.
// ---------------------------------------------------------------------------
__global__ __launch_bounds__(256) void pack_init(
    const float* __restrict__ Bm, const float* __restrict__ Lam,
    unsigned short* __restrict__ Bt, unsigned short* __restrict__ LamT,
    unsigned short* __restrict__ Phi, unsigned short* __restrict__ Plo)
{
  const int idx = blockIdx.x * 256 + threadIdx.x;  // 0..65535
  const int e = idx >> 8, d = idx & 255;
  Bt[idx]   = f2u(Bm[d * 256 + e]);
  LamT[idx] = f2u(Lam[d * 256 + e]);
  float v = Lam[idx];                              // idx as (dd,ee) row-major
  unsigned short hi = f2u(v);
  Phi[65536 + idx] = hi;
  Plo[65536 + idx] = f2u(v - u2f(hi));
  const int dd = idx >> 8, ee = idx & 255;
  Phi[idx] = (dd == ee) ? (unsigned short)0x3F80 : (unsigned short)0;
  Plo[idx] = 0;
}

// ---------------------------------------------------------------------------
// pack_all: Ghat (blocks 0..1023) + Qcat/G2/LcT2 (blocks 1024..2335).
//  Ghat[(j*256+e)][d] = P_{63-j}[d][e]
//  Qcat[2304][2048], G2[2048][256], LcT2hi/lo[e][d] = P2_8[d][e]
// ---------------------------------------------------------------------------
__global__ __launch_bounds__(256) void pack_all(
    const unsigned short* __restrict__ Phi,
    const unsigned short* __restrict__ Phi2, const unsigned short* __restrict__ Plo2,
    unsigned short* __restrict__ Ghat,
    unsigned short* __restrict__ Qcat, unsigned short* __restrict__ G2,
    unsigned short* __restrict__ LcT2hi, unsigned short* __restrict__ LcT2lo)
{
  __shared__ unsigned short tile[64][65];
  const int tx = threadIdx.x & 63, ty = threadIdx.x >> 6;  // ty 0..3
  const int blk0 = blockIdx.x;
  if (blk0 < 1024) {
    const int jpar = blk0 >> 4, t16 = blk0 & 15;
    const unsigned short* src = Phi + (size_t)(63 - jpar) * 65536;
    const int d0 = (t16 & 3) * 64, e0 = (t16 >> 2) * 64;
#pragma unroll
    for (int s = 0; s < 16; ++s)
      tile[ty*16 + s][tx] = src[(size_t)(d0 + ty*16 + s) * 256 + e0 + tx];
    __syncthreads();
#pragma unroll
    for (int s = 0; s < 16; ++s) {
      const int e = e0 + ty*16 + s, d = d0 + tx;
      Ghat[((size_t)(jpar*256 + e)) * 256 + d] = tile[tx][ty*16 + s];
    }
    return;
  }
  const int blk = blk0 - 1024;
  if (blk < 1152) {                                  // Qcat: 36x32 tiles of 64x64
    const int rt = blk >> 5, ct = blk & 31;
    const int k0 = rt * 64, c0 = ct * 64;
    const int r = c0 >> 8, d0 = c0 & 255;
    int p = 0, e0 = 0;
    bool zero = false;
    if (k0 < 256) { p = r; e0 = k0; }
    else {
      const int u = (k0 - 256) >> 8; e0 = (k0 - 256) & 255;
      if (u >= r) zero = true; else p = r - 1 - u;
    }
    if (zero) {
#pragma unroll
      for (int s = 0; s < 16; ++s)
        Qcat[(size_t)(k0 + ty*16 + s) * 2048 + c0 + tx] = 0;
      return;
    }
    const unsigned short* src = Phi2 + (size_t)p * 65536;
#pragma unroll
    for (int s = 0; s < 16; ++s)
      tile[ty*16 + s][tx] = src[(size_t)(d0 + ty*16 + s) * 256 + e0 + tx];
    __syncthreads();
#pragma unroll
    for (int s = 0; s < 16; ++s)
      Qcat[(size_t)(k0 + ty*16 + s) * 2048 + c0 + tx] = tile[tx][ty*16 + s];
  } else if (blk < 1280) {                           // G2: 32x4 tiles
    const int t = blk - 1152;
    const int rt = t >> 2, ct = t & 3;
    const int k0 = rt * 64, d0 = ct * 64;
    const int r = k0 >> 8, e0 = k0 & 255;
    const unsigned short* src = Phi2 + (size_t)(7 - r) * 65536;
#pragma unroll
    for (int s = 0; s < 16; ++s)
      tile[ty*16 + s][tx] = src[(size_t)(d0 + ty*16 + s) * 256 + e0 + tx];
    __syncthreads();
#pragma unroll
    for (int s = 0; s < 16; ++s)
      G2[(size_t)(k0 + ty*16 + s) * 256 + d0 + tx] = tile[tx][ty*16 + s];
  } else {                                           // LcT2 hi (16) + lo (16)
    const int t = blk - 1280;
    const int half = t >> 4, t16 = t & 15;
    const int d0 = (t16 & 3) * 64, e0 = (t16 >> 2) * 64;
    const unsigned short* src = (half ? Plo2 : Phi2) + (size_t)8 * 65536;
    unsigned short* dst = half ? LcT2lo : LcT2hi;
#pragma unroll
    for (int s = 0; s < 16; ++s)
      tile[ty*16 + s][tx] = src[(size_t)(d0 + ty*16 + s) * 256 + e0 + tx];
    __syncthreads();
#pragma unroll
    for (int s = 0; s < 16; ++s)
      dst[(size_t)(e0 + ty*16 + s) * 256 + d0 + tx] = tile[tx][ty*16 + s];
  }
}

// ---------------------------------------------------------------------------
// reduce split-K partials and scatter into Acat (bf16) S-region:
// s_{b, i=8m+u}[e] -> Acat[b*8+m][256 + u*256 + e]
// ---------------------------------------------------------------------------
__global__ __launch_bounds__(256) void reduce_s2(
    const float* __restrict__ Sp, unsigned short* __restrict__ Acat)
{
  const int f = blockIdx.x * 256 + threadIdx.x;   // 262144 total
  float v = 0;
#pragma unroll
  for (int z = 0; z < 8; ++z) v += Sp[(size_t)z * 262144 + f];
  const int e = f & 255, i = (f >> 8) & 63, b = f >> 14;
  const int u = i & 7, m = i >> 3;
  Acat[(size_t)(b*8 + m) * 2304 + 256 + u*256 + e] = f2u(v);
}

// ---------------------------------------------------------------------------
// Level-2 sequential combine: 8 steps, ONE workgroup, split-bf16 MFMA.
// A2_{b,m} (state entering superchunk m) written bf16 into Acat cols 0..255.
// ---------------------------------------------------------------------------
__global__ __launch_bounds__(512, 2) void k4b_combine(
    const unsigned short* __restrict__ LcT2hi, const unsigned short* __restrict__ LcT2lo,
    const float* __restrict__ S2, unsigned short* __restrict__ Acat)
{
  __shared__ unsigned short Hhi[16][264];
  __shared__ unsigned short Hlo[16][264];
  const int tid = threadIdx.x, lane = tid & 63, w = tid >> 6;  // 8 waves
  const int q = lane >> 4, ln = lane & 15;

  v8s bhi[8][2], blo[8][2];                       // (Lam^512)^T frags, cols [32w,32w+32)
#pragma unroll
  for (int kk = 0; kk < 8; ++kk)
#pragma unroll
    for (int nb = 0; nb < 2; ++nb) {
      const int n = 32*w + nb*16 + ln;
#pragma unroll
      for (int r = 0; r < 8; ++r) {
        const int k = kk*32 + q*8 + r;
        bhi[kk][nb][r] = (short)LcT2hi[k*256 + n];
        blo[kk][nb][r] = (short)LcT2lo[k*256 + n];
      }
    }
  for (int e = tid; e < 16*264; e += 512) { (&Hhi[0][0])[e] = 0; (&Hlo[0][0])[e] = 0; }
  lds_barrier();

  for (int m = 0; m < 8; ++m) {
    // A2_{b,m} = state BEFORE absorbing superchunk m
    for (int e = tid; e < 4096; e += 512) {
      const int b = e >> 8, d = e & 255;
      Acat[(size_t)(b*8 + m) * 2304 + d] = Hhi[b][d];
    }
    v8s ahi[8], alo[8];
#pragma unroll
    for (int kk = 0; kk < 8; ++kk) {
      ahi[kk] = *(const v8s*)&Hhi[ln][kk*32 + q*8];
      alo[kk] = *(const v8s*)&Hlo[ln][kk*32 + q*8];
    }
    lds_barrier();
    v4f acc[2];
#pragma unroll
    for (int nb = 0; nb < 2; ++nb)
#pragma unroll
      for (int r = 0; r < 4; ++r) {
        const int bb = 4*q + r, col = 32*w + nb*16 + ln;
        acc[nb][r] = S2[(size_t)(bb*8 + m) * 256 + col];
      }
#pragma unroll
    for (int kk = 0; kk < 8; ++kk)
#pragma unroll
      for (int nb = 0; nb < 2; ++nb) {
        acc[nb] = __builtin_amdgcn_mfma_f32_16x16x32_bf16(ahi[kk], bhi[kk][nb], acc[nb], 0, 0, 0);
        acc[nb] = __builtin_amdgcn_mfma_f32_16x16x32_bf16(alo[kk], bhi[kk][nb], acc[nb], 0, 0, 0);
        acc[nb] = __builtin_amdgcn_mfma_f32_16x16x32_bf16(ahi[kk], blo[kk][nb], acc[nb], 0, 0, 0);
      }
#pragma unroll
    for (int nb = 0; nb < 2; ++nb)
#pragma unroll
      for (int r = 0; r < 4; ++r) {
        const int bb = 4*q + r, col = 32*w + nb*16 + ln;
        float v = acc[nb][r];
        unsigned short hi = f2u(v);
        Hhi[bb][col] = hi;
        Hlo[bb][col] = f2u(v - u2f(hi));
      }
    lds_barrier();
  }
}

// ---------------------------------------------------------------------------
// Final scan: state initialized from Abf (chunk-entry states, bf16) ->
// h_j = Lam h_{j-1} + bx_j writes the FINAL output. Runs last.
// R11: chunk c state lives in gs row 4c -> D row 4c -> lane group q=c:
// epilogue spread over all 64 lanes (4 Out stores + 4 LDS writes + 4 Bx
// prefetch per lane; was 16 each on the q==0 quarter). Bit-identical math.
// 256 blocks x 4 chunk-states, double-buffered gs, ONE lds_barrier/step.
// ---------------------------------------------------------------------------
__global__ __launch_bounds__(256, 1) void k5_scan(
    const unsigned short* __restrict__ LamT,
    const unsigned short* __restrict__ Bx,
    const unsigned short* __restrict__ Abf, float* __restrict__ Out)
{
  __shared__ unsigned short gs[2][16][264];
  const int tid = threadIdx.x, lane = tid & 63, w = tid >> 6;  // 4 waves
  const int q = lane >> 4, ln = lane & 15;
  const int blk = blockIdx.x;
  const int b  = blk >> 4;            // batch
  const int i0 = (blk * 4) & 63;      // first chunk index of this block

  v8s bf[8][4];                        // Lam^T frags, cols [64w,64w+64)
#pragma unroll
  for (int kk = 0; kk < 8; ++kk)
#pragma unroll
    for (int nb = 0; nb < 4; ++nb) {
      const int n = 64*w + nb*16 + ln;
#pragma unroll
      for (int r = 0; r < 8; ++r)
        bf[kk][nb][r] = (short)LamT[(kk*32 + q*8 + r) * 256 + n];
    }
  for (int e = tid; e < 2*16*264; e += 256) (&gs[0][0][0])[e] = 0;  // zero both bufs
  lds_barrier();
  // init rows {0,4,8,12} of buf 0 with chunk-entry states A_{b,i0+r}
#pragma unroll
  for (int r = 0; r < 4; ++r)
    gs[0][4*r][tid] = Abf[((size_t)(b*64 + i0 + r)) * 256 + tid];

  // this lane's chunk = q; its Bx/Out row base:
  const size_t baseq = ((size_t)b*4096 + (size_t)(i0 + q)*64) * 256;
  const int colw = 64*w;

  unsigned short bxr[2][4];            // depth-2 Bx prefetch ring (ALL lanes)
#pragma unroll
  for (int s = 0; s < 2; ++s)
#pragma unroll
    for (int nb = 0; nb < 4; ++nb)
      bxr[s][nb] = Bx[baseq + (size_t)s*256 + colw + nb*16 + ln];
  lds_barrier();

#pragma unroll 2
  for (int j = 0; j < CHUNK; ++j) {
    v8s a[8];
#pragma unroll
    for (int kk = 0; kk < 8; ++kk) a[kk] = *(const v8s*)&gs[j & 1][ln][kk*32 + q*8];
    v4f acc[4];
#pragma unroll
    for (int nb = 0; nb < 4; ++nb) acc[nb] = 0;
#pragma unroll
    for (int kk = 0; kk < 8; ++kk)
#pragma unroll
      for (int nb = 0; nb < 4; ++nb)
        acc[nb] = __builtin_amdgcn_mfma_f32_16x16x32_bf16(a[kk], bf[kk][nb], acc[nb], 0, 0, 0);
    // epilogue: lane group q owns chunk q = D row 4q = acc[nb][0]
    {
      const size_t rb = baseq + (size_t)j*256 + colw;
#pragma unroll
      for (int nb = 0; nb < 4; ++nb) {
        const float g = acc[nb][0] + u2f(bxr[j & 1][nb]);
        Out[rb + nb*16 + ln] = g;                          // FINAL h
        gs[(j + 1) & 1][4*q][colw + nb*16 + ln] = f2u(g);  // write OTHER buffer
      }
      if (j < CHUNK - 2) {
        const size_t rb2 = baseq + (size_t)(j + 2)*256 + colw;
#pragma unroll
        for (int nb = 0; nb < 4; ++nb)
          bxr[j & 1][nb] = Bx[rb2 + nb*16 + ln];
      }
    }
    lds_barrier();   // single barrier: new state visible to all waves
  }
}

// ---------------------------------------------------------------------------
extern "C" void kernel_launch(void* const* d_in, const int* in_sizes, int n_in,
                              void* d_out, int out_size, void* d_ws, size_t ws_size,
                              hipStream_t stream)
{
  const float* x   = (const float*)d_in[0];
  const float* Bm  = (const float*)d_in[1];
  const float* Lam = (const float*)d_in[2];
  float* Out = (float*)d_out;
  (void)in_sizes; (void)n_in; (void)out_size; (void)ws_size;

  char* ws = (char*)d_ws;
  size_t off = 0;
  auto alloc = [&](size_t bytes) { void* p = ws + off; off += (bytes + 255) & ~(size_t)255; return p; };
  unsigned short* Bx    = (unsigned short*)alloc((size_t)16777216 * 2);      // 32 MB
  unsigned short* Phi   = (unsigned short*)alloc((size_t)65 * 65536 * 2);    // 8.3 MB
  unsigned short* Plo   = (unsigned short*)alloc((size_t)65 * 65536 * 2);    // 8.3 MB
  unsigned short* Ghat  = (unsigned short*)alloc((size_t)16384 * 256 * 2);   // 8 MB
  unsigned short* Qcat  = (unsigned short*)alloc((size_t)2304 * 2048 * 2);   // 9.4 MB
  unsigned short* G2    = (unsigned short*)alloc((size_t)2048 * 256 * 2);    // 1 MB
  unsigned short* Phi2  = (unsigned short*)alloc((size_t)9 * 65536 * 2);
  unsigned short* Plo2  = (unsigned short*)alloc((size_t)9 * 65536 * 2);
  unsigned short* Bt    = (unsigned short*)alloc(131072);
  unsigned short* LamT  = (unsigned short*)alloc(131072);
  unsigned short* LcT2hi= (unsigned short*)alloc(131072);
  unsigned short* LcT2lo= (unsigned short*)alloc(131072);
  unsigned short* Acat  = (unsigned short*)alloc((size_t)128 * 2304 * 2);    // 0.6 MB
  float*          S2    = (float*)alloc(131072);
  unsigned short* Abf   = (unsigned short*)alloc(524288);
  float*          Spart = (float*)Plo;  // alias: Plo dead before summary GEMM writes Spart

  // 1) packs + P0/P1
  pack_init<<<dim3(256), dim3(256), 0, stream>>>(Bm, Lam, Bt, LamT, Phi, Plo);
  // 2) Bx = x @ B^T  (bf16 out)
  gemm_tile<true, true, false><<<dim3(4, 1024, 1), dim3(256), 0, stream>>>(
      (const void*)x, Bt, (void*)Bx, 256, 256, 256, 256, 0);
  // 3) level-1 powers P_2..P_64 by doubling (mp=32 also seeds P2_0/P2_1)
  for (int mp = 1; mp <= 32; mp <<= 1)
    pow_round<<<dim3(mp * 4, 4, 1), dim3(512), 0, stream>>>(Phi, Plo, mp, Phi2, Plo2);
  // 4) level-2 powers P2_2..P2_8
  for (int mp = 1; mp <= 4; mp <<= 1)
    pow_round<<<dim3(mp * 4, 4, 1), dim3(512), 0, stream>>>(Phi2, Plo2, mp, Phi2, Plo2);
  // 5) pack GEMM operands (Ghat, Qcat, G2, LcT2)
  pack_all<<<dim3(2336), dim3(256), 0, stream>>>(Phi, Phi2, Plo2,
      Ghat, Qcat, G2, LcT2hi, LcT2lo);
  // 6) chunk summaries: S = Bx_reshaped[1024,16384] @ Ghat  (split-K=8)
  gemm_tile<false, false, false><<<dim3(4, 16, 8), dim3(256), 0, stream>>>(
      (const void*)Bx, Ghat, (void*)Spart, 16384, 256, 256, 2048, 262144);
  reduce_s2<<<dim3(1024), dim3(256), 0, stream>>>(Spart, Acat);
  // 7) level-2 summaries: S2[128,256] = Acat_S[128,2048] @ G2
  gemm_tile<false, false, false><<<dim3(4, 2, 1), dim3(256), 0, stream>>>(
      (const void*)(Acat + 256), G2, (void*)S2, 2304, 256, 256, 2048, 0);
  // 8) sequential combine over 8 superchunks -> A2 into Acat cols 0..255
  k4b_combine<<<dim3(1), dim3(512), 0, stream>>>(LcT2hi, LcT2lo, S2, Acat);
  // 9) all chunk-entry states: Abf[128,2048] = Acat[128,2304] @ Qcat
  gemm_tile<false, true, false><<<dim3(32, 2, 1), dim3(256), 0, stream>>>(
      (const void*)Acat, Qcat, (void*)Abf, 2304, 2048, 2048, 2304, 0);
  // 10) FINAL scan with chunk-entry init: Out = full h (no carry GEMM)
  k5_scan<<<dim3(256), dim3(256), 0, stream>>>(LamT, Bx, Abf, Out);
}